// Round 1
// baseline (1527.019 us; speedup 1.0000x reference)
//
#include <hip/hip_runtime.h>
#include <cstdint>

typedef __attribute__((ext_vector_type(8))) short short8;
typedef __attribute__((ext_vector_type(4))) float f32x4;
typedef unsigned short ushort_t;

constexpr int Bc = 4, Sc = 2048, Dc = 2048, Hc = 16, DKc = 128;
constexpr long NTOK = (long)Bc * Sc;          // 8192 rows
constexpr long OUT_ELEMS = NTOK * (long)Dc;   // 16777216
constexpr float SCALE = 0.08838834764831843f; // 1/sqrt(128)

__device__ __forceinline__ ushort_t f2bf(float f) {
  unsigned u = __builtin_bit_cast(unsigned, f);
  u = (u + 0x7FFFu + ((u >> 16) & 1u)) >> 16;
  return (ushort_t)u;
}

__device__ __forceinline__ short8 pack8(const f32x4& a, const f32x4& b) {
  short8 h;
  h[0] = (short)f2bf(a[0]); h[1] = (short)f2bf(a[1]);
  h[2] = (short)f2bf(a[2]); h[3] = (short)f2bf(a[3]);
  h[4] = (short)f2bf(b[0]); h[5] = (short)f2bf(b[1]);
  h[6] = (short)f2bf(b[2]); h[7] = (short)f2bf(b[3]);
  return h;
}

// async global->LDS, 16B per lane; lds dest must be wave-uniform base (+lane*16 implicit)
__device__ __forceinline__ void gl2lds16(const ushort_t* g, ushort_t* l) {
  __builtin_amdgcn_global_load_lds(
      (__attribute__((address_space(1))) unsigned int*)(g),
      (__attribute__((address_space(3))) unsigned int*)(l), 16, 0, 0);
}

// ---------------------------------------------------------------------------
// NT GEMM: C = A(MxK) * B(NxK)^T, 128x128 tile, BK=64, 4 waves, bf16 MFMA.
// All leading dims are 2048 in this problem.
// MODE 0: C bf16 row-major (projections Q,K)
// MODE 1: C = VT transposed bf16  (V projection -> VT[(h*4+b)*128+dk][s])
// MODE 2: batched scores: z=n; A=Q,B=K offset (n&3)*S*D+(n>>2)*128; C=fp32*SCALE at attn+n*S*S
// MODE 3: C fp32 + residual (output projection)
// MODE 4: batched PV: A=attn fp32 (reg-staged->bf16), B=VT; C bf16 at permuted ctx layout
// ---------------------------------------------------------------------------
template<int MODE>
__global__ __launch_bounds__(256)
void gemm_nt(const void* __restrict__ Ap, const ushort_t* __restrict__ Bp,
             void* __restrict__ Cp, const float* __restrict__ residual)
{
  constexpr int K = (MODE == 2) ? DKc : Dc;
  constexpr int NK = K / 64;

  __shared__ __align__(16) ushort_t As[128 * 64];
  __shared__ __align__(16) ushort_t Bs[128 * 64];

  const int tid  = threadIdx.x;
  const int lane = tid & 63;
  const int wave = tid >> 6;
  const int wr = wave >> 1, wc = wave & 1;
  const long m0 = (long)blockIdx.y * 128;
  const long n0 = (long)blockIdx.x * 128;
  const int bz = blockIdx.z;

  long offA = 0, offB = 0;
  if constexpr (MODE == 2) {
    offA = (long)(bz & 3) * Sc * Dc + (long)(bz >> 2) * DKc;
    offB = offA;
  }
  if constexpr (MODE == 4) {
    offA = (long)bz * Sc * Sc;
    offB = (long)bz * DKc * (long)Sc;
  }

  const ushort_t* Abf = (const ushort_t*)Ap + offA;
  const float*    Af  = (const float*)Ap + offA;
  const ushort_t* Bbf = Bp + offB;

  f32x4 acc[4][4] = {};

  for (int kt = 0; kt < NK; ++kt) {
    const int kb = kt * 64;
    __syncthreads();
    // ---- stage A tile (128 rows x 64 k), XOR-swizzled 16B units ----
    if constexpr (MODE == 4) {
      // fp32 source: reg-stage + convert, swizzled ds_write
#pragma unroll
      for (int j = 0; j < 4; ++j) {
        int U = tid * 4 + j;            // 16B unit index 0..1023
        int row = U >> 3;
        int p = U & 7;                  // physical unit in row
        int u = p ^ (row & 7);          // logical k-unit
        const float* g = Af + (m0 + row) * (long)Sc + kb + u * 8;
        f32x4 v0 = *(const f32x4*)g;
        f32x4 v1 = *(const f32x4*)(g + 4);
        *(short8*)(&As[row * 64 + p * 8]) = pack8(v0, v1);
      }
    } else {
#pragma unroll
      for (int it = 0; it < 4; ++it) {
        int chunk = it * 4 + wave;      // 1KB chunk, wave-uniform
        int o = chunk * 1024 + lane * 16;
        int row = o >> 7;
        int p = (o >> 4) & 7;
        int u = p ^ (row & 7);
        gl2lds16(Abf + (m0 + row) * (long)Dc + kb + u * 8, &As[chunk * 512]);
      }
    }
    // ---- stage B tile (always bf16 via global_load_lds) ----
#pragma unroll
    for (int it = 0; it < 4; ++it) {
      int chunk = it * 4 + wave;
      int o = chunk * 1024 + lane * 16;
      int row = o >> 7;
      int p = (o >> 4) & 7;
      int u = p ^ (row & 7);
      gl2lds16(Bbf + (n0 + row) * (long)Dc + kb + u * 8, &Bs[chunk * 512]);
    }
    __syncthreads();
    // ---- compute: 2 k-slices of 32, 16 MFMA each ----
#pragma unroll
    for (int kk = 0; kk < 2; ++kk) {
      short8 af[4], bfr[4];
#pragma unroll
      for (int m = 0; m < 4; ++m) {
        int row = wr * 64 + m * 16 + (lane & 15);
        int p = (kk * 4 + (lane >> 4)) ^ (row & 7);
        af[m] = *(const short8*)(&As[row * 64 + p * 8]);
      }
#pragma unroll
      for (int n = 0; n < 4; ++n) {
        int row = wc * 64 + n * 16 + (lane & 15);
        int p = (kk * 4 + (lane >> 4)) ^ (row & 7);
        bfr[n] = *(const short8*)(&Bs[row * 64 + p * 8]);
      }
#pragma unroll
      for (int m = 0; m < 4; ++m)
#pragma unroll
        for (int n = 0; n < 4; ++n)
          acc[m][n] = __builtin_amdgcn_mfma_f32_16x16x32_bf16(af[m], bfr[n], acc[m][n], 0, 0, 0);
    }
  }

  // ---- epilogue: C/D layout col=lane&15, row=(lane>>4)*4+reg ----
  const int c_row0 = wr * 64 + ((lane >> 4) * 4);
  const int c_col0 = wc * 64 + (lane & 15);
#pragma unroll
  for (int m = 0; m < 4; ++m) {
#pragma unroll
    for (int n = 0; n < 4; ++n) {
#pragma unroll
      for (int j = 0; j < 4; ++j) {
        long rg = m0 + c_row0 + m * 16 + j;
        long cg = n0 + c_col0 + n * 16;
        float val = acc[m][n][j];
        if constexpr (MODE == 0) {
          ((ushort_t*)Cp)[rg * (long)Dc + cg] = f2bf(val);
        } else if constexpr (MODE == 1) {
          long b = rg >> 11, s = rg & 2047;   // rg over B*S, S=2048
          long h = cg >> 7,  dk = cg & 127;   // cg over D
          ((ushort_t*)Cp)[((h * 4 + b) * 128 + dk) * (long)Sc + s] = f2bf(val);
        } else if constexpr (MODE == 2) {
          ((float*)Cp)[(long)bz * Sc * (long)Sc + rg * (long)Sc + cg] = val * SCALE;
        } else if constexpr (MODE == 3) {
          ((float*)Cp)[rg * (long)Dc + cg] = val + residual[rg * (long)Dc + cg];
        } else if constexpr (MODE == 4) {
          // context permuted: n=bz -> b_out=bz>>4, h_out=bz&15 ; rg=s, cg=dk
          ((ushort_t*)Cp)[((long)(bz >> 4) * Sc + rg) * (long)Dc + (long)(bz & 15) * DKc + cg] = f2bf(val);
        }
      }
    }
  }
}

// ---------------------------------------------------------------------------
__global__ __launch_bounds__(256)
void cast_bf16(const float* __restrict__ in, ushort_t* __restrict__ out) {
  long i = ((long)blockIdx.x * 256 + threadIdx.x) * 8;
  f32x4 a = *(const f32x4*)(in + i);
  f32x4 b = *(const f32x4*)(in + i + 4);
  *(short8*)(out + i) = pack8(a, b);
}

// in-place row softmax on (nrows, 2048) fp32; one block (256 thr) per row
__global__ __launch_bounds__(256)
void softmax_rows(float* __restrict__ attn) {
  const long row = blockIdx.x;
  float* p = attn + row * (long)Sc;
  const int tid = threadIdx.x;
  const int lane = tid & 63, wave = tid >> 6;
  f32x4 v0 = *(const f32x4*)(p + tid * 8);
  f32x4 v1 = *(const f32x4*)(p + tid * 8 + 4);
  float mx = fmaxf(fmaxf(fmaxf(v0[0], v0[1]), fmaxf(v0[2], v0[3])),
                   fmaxf(fmaxf(v1[0], v1[1]), fmaxf(v1[2], v1[3])));
  for (int off = 32; off > 0; off >>= 1) mx = fmaxf(mx, __shfl_xor(mx, off));
  __shared__ float red[4];
  if (lane == 0) red[wave] = mx;
  __syncthreads();
  mx = fmaxf(fmaxf(red[0], red[1]), fmaxf(red[2], red[3]));
  float s = 0.f;
#pragma unroll
  for (int e = 0; e < 4; ++e) { v0[e] = __expf(v0[e] - mx); s += v0[e]; }
#pragma unroll
  for (int e = 0; e < 4; ++e) { v1[e] = __expf(v1[e] - mx); s += v1[e]; }
  for (int off = 32; off > 0; off >>= 1) s += __shfl_xor(s, off);
  __syncthreads();
  if (lane == 0) red[wave] = s;
  __syncthreads();
  float inv = 1.f / (red[0] + red[1] + red[2] + red[3]);
#pragma unroll
  for (int e = 0; e < 4; ++e) { v0[e] *= inv; v1[e] *= inv; }
  *(f32x4*)(p + tid * 8) = v0;
  *(f32x4*)(p + tid * 8 + 4) = v1;
}

// in-place row layernorm on (8192, 2048) fp32
__global__ __launch_bounds__(256)
void layernorm_rows(float* __restrict__ out, const float* __restrict__ gamma,
                    const float* __restrict__ beta) {
  const long row = blockIdx.x;
  float* p = out + row * (long)Dc;
  const int tid = threadIdx.x;
  const int lane = tid & 63, wave = tid >> 6;
  f32x4 v0 = *(const f32x4*)(p + tid * 8);
  f32x4 v1 = *(const f32x4*)(p + tid * 8 + 4);
  float s = 0.f, ss = 0.f;
#pragma unroll
  for (int e = 0; e < 4; ++e) { s += v0[e]; ss += v0[e] * v0[e]; }
#pragma unroll
  for (int e = 0; e < 4; ++e) { s += v1[e]; ss += v1[e] * v1[e]; }
  for (int off = 32; off > 0; off >>= 1) { s += __shfl_xor(s, off); ss += __shfl_xor(ss, off); }
  __shared__ float rs[4], rss[4];
  if (lane == 0) { rs[wave] = s; rss[wave] = ss; }
  __syncthreads();
  s  = rs[0] + rs[1] + rs[2] + rs[3];
  ss = rss[0] + rss[1] + rss[2] + rss[3];
  const float mean = s * (1.f / Dc);
  const float var  = ss * (1.f / Dc) - mean * mean;
  const float rstd = rsqrtf(var + 1e-6f);
  f32x4 g0 = *(const f32x4*)(gamma + tid * 8);
  f32x4 g1 = *(const f32x4*)(gamma + tid * 8 + 4);
  f32x4 b0 = *(const f32x4*)(beta + tid * 8);
  f32x4 b1 = *(const f32x4*)(beta + tid * 8 + 4);
#pragma unroll
  for (int e = 0; e < 4; ++e) v0[e] = (v0[e] - mean) * rstd * g0[e] + b0[e];
#pragma unroll
  for (int e = 0; e < 4; ++e) v1[e] = (v1[e] - mean) * rstd * g1[e] + b1[e];
  *(f32x4*)(p + tid * 8) = v0;
  *(f32x4*)(p + tid * 8 + 4) = v1;
}

// ---------------------------------------------------------------------------
extern "C" void kernel_launch(void* const* d_in, const int* in_sizes, int n_in,
                              void* d_out, int out_size, void* d_ws, size_t ws_size,
                              hipStream_t stream) {
  (void)in_sizes; (void)n_in; (void)out_size; (void)ws_size;
  const float* q  = (const float*)d_in[0];
  const float* k  = (const float*)d_in[1];
  const float* v  = (const float*)d_in[2];
  const float* Wq = (const float*)d_in[3];
  const float* Wk = (const float*)d_in[4];
  const float* Wv = (const float*)d_in[5];
  const float* Wo = (const float*)d_in[6];
  const float* gamma = (const float*)d_in[7];
  const float* beta  = (const float*)d_in[8];

  float* out  = (float*)d_out;
  float* attn = out + OUT_ELEMS;                // 1.07 GB region (output 1)

  // workspace layout (160 MB)
  ushort_t* Wqb = (ushort_t*)d_ws;
  ushort_t* Wkb = Wqb + (long)Dc * Dc;
  ushort_t* Wvb = Wkb + (long)Dc * Dc;
  ushort_t* Wob = Wvb + (long)Dc * Dc;
  ushort_t* Qb  = Wob + (long)Dc * Dc;
  ushort_t* Kb  = Qb + OUT_ELEMS;
  ushort_t* VT  = Kb + OUT_ELEMS;
  ushort_t* Cb  = VT + OUT_ELEMS;

  // bf16 copies of q,k,v parked in the attn region (dead before scores write it)
  ushort_t* qb = (ushort_t*)attn;
  ushort_t* kb = qb + OUT_ELEMS;
  ushort_t* vb = kb + OUT_ELEMS;

  dim3 blk(256);
  // casts (8 fp32/thread)
  cast_bf16<<<OUT_ELEMS / 2048, blk, 0, stream>>>(q, qb);
  cast_bf16<<<OUT_ELEMS / 2048, blk, 0, stream>>>(k, kb);
  cast_bf16<<<OUT_ELEMS / 2048, blk, 0, stream>>>(v, vb);
  cast_bf16<<<(long)Dc * Dc / 2048, blk, 0, stream>>>(Wq, Wqb);
  cast_bf16<<<(long)Dc * Dc / 2048, blk, 0, stream>>>(Wk, Wkb);
  cast_bf16<<<(long)Dc * Dc / 2048, blk, 0, stream>>>(Wv, Wvb);
  cast_bf16<<<(long)Dc * Dc / 2048, blk, 0, stream>>>(Wo, Wob);

  // projections
  gemm_nt<0><<<dim3(16, 64, 1), blk, 0, stream>>>(qb, Wqb, Qb, nullptr);
  gemm_nt<0><<<dim3(16, 64, 1), blk, 0, stream>>>(kb, Wkb, Kb, nullptr);
  gemm_nt<1><<<dim3(16, 64, 1), blk, 0, stream>>>(vb, Wvb, VT, nullptr);

  // scores (raw, scaled) into attn region, batched over n = h*4+b
  gemm_nt<2><<<dim3(16, 16, 64), blk, 0, stream>>>(Qb, Kb, attn, nullptr);

  // softmax in place (64*2048 rows)
  softmax_rows<<<64 * Sc, blk, 0, stream>>>(attn);

  // context = attn @ V  (writes permuted context layout)
  gemm_nt<4><<<dim3(1, 16, 64), blk, 0, stream>>>(attn, VT, Cb, nullptr);

  // output projection + residual
  gemm_nt<3><<<dim3(16, 64, 1), blk, 0, stream>>>(Cb, Wob, out, q);

  // layernorm in place
  layernorm_rows<<<NTOK, blk, 0, stream>>>(out, gamma, beta);
}

// Round 2
// 1419.797 us; speedup vs baseline: 1.0755x; 1.0755x over previous
//
#include <hip/hip_runtime.h>
#include <cstdint>

typedef __attribute__((ext_vector_type(8))) short short8;
typedef __attribute__((ext_vector_type(4))) float f32x4;
typedef unsigned short ushort_t;

constexpr int Bc = 4, Sc = 2048, Dc = 2048, Hc = 16, DKc = 128;
constexpr long NTOK = (long)Bc * Sc;          // 8192 rows
constexpr long OUT_ELEMS = NTOK * (long)Dc;   // 16777216
constexpr float SCALE = 0.08838834764831843f; // 1/sqrt(128)

__device__ __forceinline__ ushort_t f2bf(float f) {
  unsigned u = __builtin_bit_cast(unsigned, f);
  u = (u + 0x7FFFu + ((u >> 16) & 1u)) >> 16;
  return (ushort_t)u;
}

__device__ __forceinline__ short8 pack8(const f32x4& a, const f32x4& b) {
  short8 h;
  h[0] = (short)f2bf(a[0]); h[1] = (short)f2bf(a[1]);
  h[2] = (short)f2bf(a[2]); h[3] = (short)f2bf(a[3]);
  h[4] = (short)f2bf(b[0]); h[5] = (short)f2bf(b[1]);
  h[6] = (short)f2bf(b[2]); h[7] = (short)f2bf(b[3]);
  return h;
}

// async global->LDS, 16B per lane; lds dest must be wave-uniform base (+lane*16 implicit)
__device__ __forceinline__ void gl2lds16(const ushort_t* g, ushort_t* l) {
  __builtin_amdgcn_global_load_lds(
      (__attribute__((address_space(1))) unsigned int*)(g),
      (__attribute__((address_space(3))) unsigned int*)(l), 16, 0, 0);
}

// ---------------------------------------------------------------------------
// NT GEMM: C = A(MxK) * B(NxK)^T, 128x128 tile, BK=64, 4 waves, bf16 MFMA.
// MODE 0: C bf16 row-major (projections Q,K)
// MODE 1: C = VT transposed bf16  (V projection -> VT[(h*4+b)*128+dk][s])
// MODE 2: batched scores: z=n; A=Q,B=K offset (n&3)*S*D+(n>>2)*128;
//         C = exp(s*SCALE) fp32 at attn+n*S*S, partial rowsums -> part
// MODE 3: C fp32 + residual (output projection)
// MODE 5: batched PV + normalize: A=exp-scores fp32; stage multiplies by
//         invl (residual param) and writes normalized attn back in place;
//         B=VT; C bf16 at permuted ctx layout
// ---------------------------------------------------------------------------
template<int MODE>
__global__ __launch_bounds__(256)
void gemm_nt(const void* __restrict__ Ap, const ushort_t* __restrict__ Bp,
             void* __restrict__ Cp, const float* __restrict__ residual,
             float* __restrict__ part)
{
  constexpr int K = (MODE == 2) ? DKc : Dc;
  constexpr int NK = K / 64;

  __shared__ __align__(16) ushort_t As[128 * 64];
  __shared__ __align__(16) ushort_t Bs[128 * 64];

  const int tid  = threadIdx.x;
  const int lane = tid & 63;
  const int wave = tid >> 6;
  const int wr = wave >> 1, wc = wave & 1;
  const long m0 = (long)blockIdx.y * 128;
  const long n0 = (long)blockIdx.x * 128;
  const int bz = blockIdx.z;

  long offA = 0, offB = 0;
  if constexpr (MODE == 2) {
    offA = (long)(bz & 3) * Sc * Dc + (long)(bz >> 2) * DKc;
    offB = offA;
  }
  if constexpr (MODE == 5) {
    offA = (long)bz * Sc * Sc;
    offB = (long)bz * DKc * (long)Sc;
  }

  const ushort_t* Abf = (const ushort_t*)Ap + offA;
  const float*    Af  = (const float*)Ap + offA;
  const ushort_t* Bbf = Bp + offB;

  f32x4 acc[4][4] = {};

  for (int kt = 0; kt < NK; ++kt) {
    const int kb = kt * 64;
    __syncthreads();
    // ---- stage A tile (128 rows x 64 k), XOR-swizzled 16B units ----
    if constexpr (MODE == 5) {
      // fp32 exp-scores: normalize, write back (in place), convert to LDS bf16
#pragma unroll
      for (int j = 0; j < 4; ++j) {
        int U = tid * 4 + j;            // dest 16B unit index 0..1023
        int row = U >> 3;
        int p = U & 7;                  // physical unit in row
        int u = p ^ (row & 7);          // logical k-unit
        float* g = (float*)(Af + (m0 + row) * (long)Sc + kb + u * 8);
        f32x4 v0 = *(const f32x4*)g;
        f32x4 v1 = *(const f32x4*)(g + 4);
        const float il = residual[(long)bz * Sc + m0 + row];
#pragma unroll
        for (int e = 0; e < 4; ++e) { v0[e] *= il; v1[e] *= il; }
        *(f32x4*)g = v0;
        *(f32x4*)(g + 4) = v1;
        *(short8*)(&As[row * 64 + p * 8]) = pack8(v0, v1);
      }
    } else {
#pragma unroll
      for (int it = 0; it < 4; ++it) {
        int chunk = it * 4 + wave;      // 1KB chunk, wave-uniform
        int o = chunk * 1024 + lane * 16;
        int row = o >> 7;
        int p = (o >> 4) & 7;
        int u = p ^ (row & 7);
        gl2lds16(Abf + (m0 + row) * (long)Dc + kb + u * 8, &As[chunk * 512]);
      }
    }
    // ---- stage B tile (always bf16 via global_load_lds) ----
#pragma unroll
    for (int it = 0; it < 4; ++it) {
      int chunk = it * 4 + wave;
      int o = chunk * 1024 + lane * 16;
      int row = o >> 7;
      int p = (o >> 4) & 7;
      int u = p ^ (row & 7);
      gl2lds16(Bbf + (n0 + row) * (long)Dc + kb + u * 8, &Bs[chunk * 512]);
    }
    __syncthreads();
    // ---- compute: 2 k-slices of 32, 16 MFMA each ----
#pragma unroll
    for (int kk = 0; kk < 2; ++kk) {
      short8 af[4], bfr[4];
#pragma unroll
      for (int m = 0; m < 4; ++m) {
        int row = wr * 64 + m * 16 + (lane & 15);
        int p = (kk * 4 + (lane >> 4)) ^ (row & 7);
        af[m] = *(const short8*)(&As[row * 64 + p * 8]);
      }
#pragma unroll
      for (int n = 0; n < 4; ++n) {
        int row = wc * 64 + n * 16 + (lane & 15);
        int p = (kk * 4 + (lane >> 4)) ^ (row & 7);
        bfr[n] = *(const short8*)(&Bs[row * 64 + p * 8]);
      }
#pragma unroll
      for (int m = 0; m < 4; ++m)
#pragma unroll
        for (int n = 0; n < 4; ++n)
          acc[m][n] = __builtin_amdgcn_mfma_f32_16x16x32_bf16(af[m], bfr[n], acc[m][n], 0, 0, 0);
    }
  }

  // ---- epilogue: C/D layout col=lane&15, row=(lane>>4)*4+reg ----
  const int c_row0 = wr * 64 + ((lane >> 4) * 4);
  const int c_col0 = wc * 64 + (lane & 15);

  if constexpr (MODE == 2) {
    // exp(scores*SCALE) + per-(row, block, wave-col-half) partial sums
    float* C = (float*)Cp + (long)bz * Sc * (long)Sc;
#pragma unroll
    for (int m = 0; m < 4; ++m) {
#pragma unroll
      for (int j = 0; j < 4; ++j) {
        const long rg = m0 + c_row0 + m * 16 + j;
        float rsum = 0.f;
#pragma unroll
        for (int n = 0; n < 4; ++n) {
          const long cg = n0 + c_col0 + n * 16;
          float e = __expf(acc[m][n][j] * SCALE);
          C[rg * (long)Sc + cg] = e;
          rsum += e;
        }
#pragma unroll
        for (int off = 1; off < 16; off <<= 1) rsum += __shfl_xor(rsum, off);
        if ((lane & 15) == 0)
          part[(((long)bz * 16 + blockIdx.x) * 2 + wc) * (long)Sc + rg] = rsum;
      }
    }
  } else {
#pragma unroll
    for (int m = 0; m < 4; ++m) {
#pragma unroll
      for (int n = 0; n < 4; ++n) {
#pragma unroll
        for (int j = 0; j < 4; ++j) {
          long rg = m0 + c_row0 + m * 16 + j;
          long cg = n0 + c_col0 + n * 16;
          float val = acc[m][n][j];
          if constexpr (MODE == 0) {
            ((ushort_t*)Cp)[rg * (long)Dc + cg] = f2bf(val);
          } else if constexpr (MODE == 1) {
            long b = rg >> 11, s = rg & 2047;   // rg over B*S, S=2048
            long h = cg >> 7,  dk = cg & 127;   // cg over D
            ((ushort_t*)Cp)[((h * 4 + b) * 128 + dk) * (long)Sc + s] = f2bf(val);
          } else if constexpr (MODE == 3) {
            ((float*)Cp)[rg * (long)Dc + cg] = val + residual[rg * (long)Dc + cg];
          } else if constexpr (MODE == 5) {
            // context permuted: n=bz -> b_out=bz>>4, h_out=bz&15 ; rg=s, cg=dk
            ((ushort_t*)Cp)[((long)(bz >> 4) * Sc + rg) * (long)Dc + (long)(bz & 15) * DKc + cg] = f2bf(val);
          }
        }
      }
    }
  }
}

// ---------------------------------------------------------------------------
__global__ __launch_bounds__(256)
void cast_bf16(const float* __restrict__ in, ushort_t* __restrict__ out) {
  long i = ((long)blockIdx.x * 256 + threadIdx.x) * 8;
  f32x4 a = *(const f32x4*)(in + i);
  f32x4 b = *(const f32x4*)(in + i + 4);
  *(short8*)(out + i) = pack8(a, b);
}

// invl[h][row] = 1 / sum over (16 n-blocks x 2 wave-halves) of partial sums
__global__ __launch_bounds__(256)
void reduce_invl(const float* __restrict__ part, float* __restrict__ invl) {
  const int i = blockIdx.x * 256 + threadIdx.x;   // 0 .. 64*2048-1
  const int h = i >> 11, r = i & 2047;
  float s = 0.f;
#pragma unroll
  for (int nx = 0; nx < 16; ++nx) {
    s += part[(((long)h * 16 + nx) * 2 + 0) * (long)Sc + r];
    s += part[(((long)h * 16 + nx) * 2 + 1) * (long)Sc + r];
  }
  invl[i] = 1.f / s;
}

// in-place row layernorm on (8192, 2048) fp32
__global__ __launch_bounds__(256)
void layernorm_rows(float* __restrict__ out, const float* __restrict__ gamma,
                    const float* __restrict__ beta) {
  const long row = blockIdx.x;
  float* p = out + row * (long)Dc;
  const int tid = threadIdx.x;
  const int lane = tid & 63, wave = tid >> 6;
  f32x4 v0 = *(const f32x4*)(p + tid * 8);
  f32x4 v1 = *(const f32x4*)(p + tid * 8 + 4);
  float s = 0.f, ss = 0.f;
#pragma unroll
  for (int e = 0; e < 4; ++e) { s += v0[e]; ss += v0[e] * v0[e]; }
#pragma unroll
  for (int e = 0; e < 4; ++e) { s += v1[e]; ss += v1[e] * v1[e]; }
  for (int off = 32; off > 0; off >>= 1) { s += __shfl_xor(s, off); ss += __shfl_xor(ss, off); }
  __shared__ float rs[4], rss[4];
  if (lane == 0) { rs[wave] = s; rss[wave] = ss; }
  __syncthreads();
  s  = rs[0] + rs[1] + rs[2] + rs[3];
  ss = rss[0] + rss[1] + rss[2] + rss[3];
  const float mean = s * (1.f / Dc);
  const float var  = ss * (1.f / Dc) - mean * mean;
  const float rstd = rsqrtf(var + 1e-6f);
  f32x4 g0 = *(const f32x4*)(gamma + tid * 8);
  f32x4 g1 = *(const f32x4*)(gamma + tid * 8 + 4);
  f32x4 b0 = *(const f32x4*)(beta + tid * 8);
  f32x4 b1 = *(const f32x4*)(beta + tid * 8 + 4);
#pragma unroll
  for (int e = 0; e < 4; ++e) v0[e] = (v0[e] - mean) * rstd * g0[e] + b0[e];
#pragma unroll
  for (int e = 0; e < 4; ++e) v1[e] = (v1[e] - mean) * rstd * g1[e] + b1[e];
  *(f32x4*)(p + tid * 8) = v0;
  *(f32x4*)(p + tid * 8 + 4) = v1;
}

// ---------------------------------------------------------------------------
extern "C" void kernel_launch(void* const* d_in, const int* in_sizes, int n_in,
                              void* d_out, int out_size, void* d_ws, size_t ws_size,
                              hipStream_t stream) {
  (void)in_sizes; (void)n_in; (void)out_size; (void)ws_size;
  const float* q  = (const float*)d_in[0];
  const float* k  = (const float*)d_in[1];
  const float* v  = (const float*)d_in[2];
  const float* Wq = (const float*)d_in[3];
  const float* Wk = (const float*)d_in[4];
  const float* Wv = (const float*)d_in[5];
  const float* Wo = (const float*)d_in[6];
  const float* gamma = (const float*)d_in[7];
  const float* beta  = (const float*)d_in[8];

  float* out  = (float*)d_out;
  float* attn = out + OUT_ELEMS;                // 4.3 GB region (output 1)

  // workspace layout (~168 MB)
  ushort_t* Wqb = (ushort_t*)d_ws;
  ushort_t* Wkb = Wqb + (long)Dc * Dc;
  ushort_t* Wvb = Wkb + (long)Dc * Dc;
  ushort_t* Wob = Wvb + (long)Dc * Dc;
  ushort_t* Qb  = Wob + (long)Dc * Dc;
  ushort_t* Kb  = Qb + OUT_ELEMS;
  ushort_t* VT  = Kb + OUT_ELEMS;
  ushort_t* Cb  = VT + OUT_ELEMS;

  // bf16 copies of q,k,v parked in the attn region (dead before scores write it)
  ushort_t* qb = (ushort_t*)attn;
  ushort_t* kb = qb + OUT_ELEMS;
  ushort_t* vb = kb + OUT_ELEMS;

  // partial rowsums overlaid on Cb (dead before PV writes context there)
  float* part = (float*)Cb;                     // 64*16*2*2048 f32 = 16.8 MB
  // invl parked at the head of the output region (dead before out-proj writes)
  float* invl = out;                            // 64*2048 f32 = 512 KB

  dim3 blk(256);
  // casts (8 fp32/thread)
  cast_bf16<<<OUT_ELEMS / 2048, blk, 0, stream>>>(q, qb);
  cast_bf16<<<OUT_ELEMS / 2048, blk, 0, stream>>>(k, kb);
  cast_bf16<<<OUT_ELEMS / 2048, blk, 0, stream>>>(v, vb);
  cast_bf16<<<(long)Dc * Dc / 2048, blk, 0, stream>>>(Wq, Wqb);
  cast_bf16<<<(long)Dc * Dc / 2048, blk, 0, stream>>>(Wk, Wkb);
  cast_bf16<<<(long)Dc * Dc / 2048, blk, 0, stream>>>(Wv, Wvb);
  cast_bf16<<<(long)Dc * Dc / 2048, blk, 0, stream>>>(Wo, Wob);

  // projections
  gemm_nt<0><<<dim3(16, 64, 1), blk, 0, stream>>>(qb, Wqb, Qb, nullptr, nullptr);
  gemm_nt<0><<<dim3(16, 64, 1), blk, 0, stream>>>(kb, Wkb, Kb, nullptr, nullptr);
  gemm_nt<1><<<dim3(16, 64, 1), blk, 0, stream>>>(vb, Wvb, VT, nullptr, nullptr);

  // exp-scores (unnormalized) into attn region + partial rowsums
  gemm_nt<2><<<dim3(16, 16, 64), blk, 0, stream>>>(Qb, Kb, attn, nullptr, part);

  // row-sum reduce -> 1/l
  reduce_invl<<<64 * Sc / 256, blk, 0, stream>>>(part, invl);

  // context = P @ V; normalizes attn in place during A-staging
  gemm_nt<5><<<dim3(1, 16, 64), blk, 0, stream>>>(attn, VT, Cb, invl, nullptr);

  // output projection + residual
  gemm_nt<3><<<dim3(16, 64, 1), blk, 0, stream>>>(Cb, Wob, out, q, nullptr);

  // layernorm in place
  layernorm_rows<<<NTOK, blk, 0, stream>>>(out, gamma, beta);
}

// Round 3
// 974.284 us; speedup vs baseline: 1.5673x; 1.4573x over previous
//
#include <hip/hip_runtime.h>
#include <cstdint>

typedef __attribute__((ext_vector_type(8))) short short8;
typedef __attribute__((ext_vector_type(4))) float f32x4;
typedef unsigned short ushort_t;

constexpr int Bc = 4, Sc = 2048, Dc = 2048, Hc = 16, DKc = 128;
constexpr long NTOK = (long)Bc * Sc;          // 8192 rows
constexpr long OUT_ELEMS = NTOK * (long)Dc;   // 16777216
constexpr float SCALE = 0.08838834764831843f; // 1/sqrt(128)

__device__ __forceinline__ ushort_t f2bf(float f) {
  unsigned u = __builtin_bit_cast(unsigned, f);
  u = (u + 0x7FFFu + ((u >> 16) & 1u)) >> 16;
  return (ushort_t)u;
}

__device__ __forceinline__ short8 pack8(const f32x4& a, const f32x4& b) {
  short8 h;
  h[0] = (short)f2bf(a[0]); h[1] = (short)f2bf(a[1]);
  h[2] = (short)f2bf(a[2]); h[3] = (short)f2bf(a[3]);
  h[4] = (short)f2bf(b[0]); h[5] = (short)f2bf(b[1]);
  h[6] = (short)f2bf(b[2]); h[7] = (short)f2bf(b[3]);
  return h;
}

// async global->LDS, 16B per lane; lds dest is wave-uniform base + lane*16
__device__ __forceinline__ void gl2lds16(const ushort_t* g, ushort_t* l) {
  __builtin_amdgcn_global_load_lds(
      (__attribute__((address_space(1))) unsigned int*)(g),
      (__attribute__((address_space(3))) unsigned int*)(l), 16, 0, 0);
}

// ---------------------------------------------------------------------------
// NT GEMM: C = A(MxK) * B(NxK)^T, 128x128 tile, BK=64, 4 waves, bf16 MFMA.
// MODE 0: C bf16 row-major (projections Q,K)
// MODE 1: C = VT transposed bf16  (V projection -> VT[(h*4+b)*128+dk][s])
// MODE 3: C fp32 + residual (output projection)
// ---------------------------------------------------------------------------
template<int MODE>
__global__ __launch_bounds__(256)
void gemm_nt(const void* __restrict__ Ap, const ushort_t* __restrict__ Bp,
             void* __restrict__ Cp, const float* __restrict__ residual)
{
  constexpr int NK = Dc / 64;

  __shared__ __align__(16) ushort_t As[128 * 64];
  __shared__ __align__(16) ushort_t Bs[128 * 64];

  const int tid  = threadIdx.x;
  const int lane = tid & 63;
  const int wave = tid >> 6;
  const int wr = wave >> 1, wc = wave & 1;
  const long m0 = (long)blockIdx.y * 128;
  const long n0 = (long)blockIdx.x * 128;

  const ushort_t* Abf = (const ushort_t*)Ap;
  const ushort_t* Bbf = Bp;

  f32x4 acc[4][4] = {};

  for (int kt = 0; kt < NK; ++kt) {
    const int kb = kt * 64;
    __syncthreads();
#pragma unroll
    for (int it = 0; it < 4; ++it) {
      int chunk = it * 4 + wave;      // 1KB chunk, wave-uniform
      int o = chunk * 1024 + lane * 16;
      int row = o >> 7;
      int p = (o >> 4) & 7;
      int u = p ^ (row & 7);
      gl2lds16(Abf + (m0 + row) * (long)Dc + kb + u * 8, &As[chunk * 512]);
    }
#pragma unroll
    for (int it = 0; it < 4; ++it) {
      int chunk = it * 4 + wave;
      int o = chunk * 1024 + lane * 16;
      int row = o >> 7;
      int p = (o >> 4) & 7;
      int u = p ^ (row & 7);
      gl2lds16(Bbf + (n0 + row) * (long)Dc + kb + u * 8, &Bs[chunk * 512]);
    }
    __syncthreads();
#pragma unroll
    for (int kk = 0; kk < 2; ++kk) {
      short8 af[4], bfr[4];
#pragma unroll
      for (int m = 0; m < 4; ++m) {
        int row = wr * 64 + m * 16 + (lane & 15);
        int p = (kk * 4 + (lane >> 4)) ^ (row & 7);
        af[m] = *(const short8*)(&As[row * 64 + p * 8]);
      }
#pragma unroll
      for (int n = 0; n < 4; ++n) {
        int row = wc * 64 + n * 16 + (lane & 15);
        int p = (kk * 4 + (lane >> 4)) ^ (row & 7);
        bfr[n] = *(const short8*)(&Bs[row * 64 + p * 8]);
      }
#pragma unroll
      for (int m = 0; m < 4; ++m)
#pragma unroll
        for (int n = 0; n < 4; ++n)
          acc[m][n] = __builtin_amdgcn_mfma_f32_16x16x32_bf16(af[m], bfr[n], acc[m][n], 0, 0, 0);
    }
  }

  const int c_row0 = wr * 64 + ((lane >> 4) * 4);
  const int c_col0 = wc * 64 + (lane & 15);
#pragma unroll
  for (int m = 0; m < 4; ++m) {
#pragma unroll
    for (int n = 0; n < 4; ++n) {
#pragma unroll
      for (int j = 0; j < 4; ++j) {
        long rg = m0 + c_row0 + m * 16 + j;
        long cg = n0 + c_col0 + n * 16;
        float val = acc[m][n][j];
        if constexpr (MODE == 0) {
          ((ushort_t*)Cp)[rg * (long)Dc + cg] = f2bf(val);
        } else if constexpr (MODE == 1) {
          long b = rg >> 11, s = rg & 2047;   // rg over B*S, S=2048
          long h = cg >> 7,  dk = cg & 127;   // cg over D
          ((ushort_t*)Cp)[((h * 4 + b) * 128 + dk) * (long)Sc + s] = f2bf(val);
        } else if constexpr (MODE == 3) {
          ((float*)Cp)[rg * (long)Dc + cg] = val + residual[rg * (long)Dc + cg];
        }
      }
    }
  }
}

// ---------------------------------------------------------------------------
// Flash attention: one block per (n=h*4+b, m-tile of 128 q-rows).
// Loop A: rowsums of exp(QK^T*scale). Loop B: recompute, write normalized
// fp32 P to attn (only attn write), PV accumulate via LDS bf16 P.
// LDS: Qs 32K + Ks 16K + Vs 16K + Ps 16K = 80KB -> 2 blocks/CU.
// ---------------------------------------------------------------------------
__global__ __launch_bounds__(256, 2)
void flash_attn(const ushort_t* __restrict__ Qb, const ushort_t* __restrict__ Kb,
                const ushort_t* __restrict__ VT, float* __restrict__ attn,
                ushort_t* __restrict__ Cb)
{
  __shared__ __align__(16) ushort_t Qs[128 * 128]; // 128 rows x 16 units, swz u^(row&15)
  __shared__ __align__(16) ushort_t Ks[64 * 128];  // 64 rows x 16 units,  swz u^(row&15)
  __shared__ __align__(16) ushort_t Vs[128 * 64];  // 128 dk x 8 units,    swz u^(row&7)
  __shared__ __align__(16) ushort_t Ps[128 * 64];  // 128 m  x 8 units,    swz u^(row&7)

  const int tid = threadIdx.x, lane = tid & 63, wave = tid >> 6;
  const int wr = wave >> 1, wc = wave & 1;

  // XCD-grouped mapping: 8 n's per XCD, 16 m-blocks of same n colocated
  const int bid = blockIdx.x;
  const int xcd = bid & 7, slot = bid >> 3;
  const int n = xcd * 8 + (slot >> 4);
  const long m0 = (long)(slot & 15) * 128;
  const int b = n & 3, h = n >> 2;

  const ushort_t* Qg = Qb + ((long)b * Sc) * Dc + (long)h * DKc;
  const ushort_t* Kg = Kb + ((long)b * Sc) * Dc + (long)h * DKc;
  const ushort_t* Vg = VT + (long)n * DKc * (long)Sc;
  float* Pg = attn + (long)n * Sc * (long)Sc;

  // ---- stage Q tile once (2048 16B units) ----
#pragma unroll
  for (int c8 = 0; c8 < 8; ++c8) {
    int chunk = c8 * 4 + wave;
    int U = chunk * 64 + lane;
    int row = U >> 4, p = U & 15, u = p ^ (row & 15);
    gl2lds16(Qg + (m0 + row) * (long)Dc + u * 8, &Qs[chunk * 512]);
  }

  float rs[4][4] = {};

  // ---- Loop A: rowsums ----
  for (int t = 0; t < 32; ++t) {
    __syncthreads();
#pragma unroll
    for (int c4 = 0; c4 < 4; ++c4) {
      int chunk = c4 * 4 + wave;
      int U = chunk * 64 + lane;
      int row = U >> 4, p = U & 15, u = p ^ (row & 15);
      gl2lds16(Kg + ((long)t * 64 + row) * (long)Dc + u * 8, &Ks[chunk * 512]);
    }
    __syncthreads();
    f32x4 acc[4][2] = {};
#pragma unroll
    for (int kk = 0; kk < 4; ++kk) {
      short8 af[4], bfr[2];
#pragma unroll
      for (int m = 0; m < 4; ++m) {
        int row = wr * 64 + m * 16 + (lane & 15);
        int p = (kk * 4 + (lane >> 4)) ^ (row & 15);
        af[m] = *(const short8*)(&Qs[row * 128 + p * 8]);
      }
#pragma unroll
      for (int nn = 0; nn < 2; ++nn) {
        int row = wc * 32 + nn * 16 + (lane & 15);
        int p = (kk * 4 + (lane >> 4)) ^ (row & 15);
        bfr[nn] = *(const short8*)(&Ks[row * 128 + p * 8]);
      }
#pragma unroll
      for (int m = 0; m < 4; ++m)
#pragma unroll
        for (int nn = 0; nn < 2; ++nn)
          acc[m][nn] = __builtin_amdgcn_mfma_f32_16x16x32_bf16(af[m], bfr[nn], acc[m][nn], 0, 0, 0);
    }
#pragma unroll
    for (int m = 0; m < 4; ++m)
#pragma unroll
      for (int nn = 0; nn < 2; ++nn)
#pragma unroll
        for (int j = 0; j < 4; ++j)
          rs[m][j] += __expf(acc[m][nn][j] * SCALE);
  }

  // reduce rowsums: within 16-lane col group, then across the two wc waves
  float* red = (float*)Ps;   // Ps dead until loop B
#pragma unroll
  for (int m = 0; m < 4; ++m)
#pragma unroll
    for (int j = 0; j < 4; ++j) {
#pragma unroll
      for (int off = 1; off < 16; off <<= 1)
        rs[m][j] += __shfl_xor(rs[m][j], off);
    }
  if ((lane & 15) == 0) {
#pragma unroll
    for (int m = 0; m < 4; ++m)
#pragma unroll
      for (int j = 0; j < 4; ++j)
        red[wc * 128 + wr * 64 + m * 16 + ((lane >> 4) * 4) + j] = rs[m][j];
  }
  __syncthreads();
  float invl[4][4];
#pragma unroll
  for (int m = 0; m < 4; ++m)
#pragma unroll
    for (int j = 0; j < 4; ++j) {
      int row = wr * 64 + m * 16 + ((lane >> 4) * 4) + j;
      invl[m][j] = 1.f / (red[row] + red[128 + row]);
    }
  __syncthreads();   // red reads done before Ps writes in loop B

  // ---- Loop B: recompute + write normalized P + PV ----
  f32x4 acco[4][4] = {};
  for (int t = 0; t < 32; ++t) {
    __syncthreads();
#pragma unroll
    for (int c4 = 0; c4 < 4; ++c4) {
      int chunk = c4 * 4 + wave;
      int U = chunk * 64 + lane;
      int row = U >> 4, p = U & 15, u = p ^ (row & 15);
      gl2lds16(Kg + ((long)t * 64 + row) * (long)Dc + u * 8, &Ks[chunk * 512]);
    }
#pragma unroll
    for (int c4 = 0; c4 < 4; ++c4) {
      int chunk = c4 * 4 + wave;
      int U = chunk * 64 + lane;
      int row = U >> 3, p = U & 7, u = p ^ (row & 7);
      gl2lds16(Vg + (long)row * Sc + (long)t * 64 + u * 8, &Vs[chunk * 512]);
    }
    __syncthreads();
    f32x4 acc[4][2] = {};
#pragma unroll
    for (int kk = 0; kk < 4; ++kk) {
      short8 af[4], bfr[2];
#pragma unroll
      for (int m = 0; m < 4; ++m) {
        int row = wr * 64 + m * 16 + (lane & 15);
        int p = (kk * 4 + (lane >> 4)) ^ (row & 15);
        af[m] = *(const short8*)(&Qs[row * 128 + p * 8]);
      }
#pragma unroll
      for (int nn = 0; nn < 2; ++nn) {
        int row = wc * 32 + nn * 16 + (lane & 15);
        int p = (kk * 4 + (lane >> 4)) ^ (row & 15);
        bfr[nn] = *(const short8*)(&Ks[row * 128 + p * 8]);
      }
#pragma unroll
      for (int m = 0; m < 4; ++m)
#pragma unroll
        for (int nn = 0; nn < 2; ++nn)
          acc[m][nn] = __builtin_amdgcn_mfma_f32_16x16x32_bf16(af[m], bfr[nn], acc[m][nn], 0, 0, 0);
    }
    // normalized P: global fp32 store + swizzled LDS bf16
#pragma unroll
    for (int m = 0; m < 4; ++m) {
#pragma unroll
      for (int nn = 0; nn < 2; ++nn) {
#pragma unroll
        for (int j = 0; j < 4; ++j) {
          float e = __expf(acc[m][nn][j] * SCALE) * invl[m][j];
          int row = wr * 64 + m * 16 + ((lane >> 4) * 4) + j;
          int col = wc * 32 + nn * 16 + (lane & 15);
          Pg[(m0 + row) * (long)Sc + (long)t * 64 + col] = e;
          int pp = (col >> 3) ^ (row & 7);
          Ps[row * 64 + pp * 8 + (col & 7)] = (ushort_t)f2bf(e);
        }
      }
    }
    __syncthreads();
    // PV: acco += P(m x 64) * V^T(dk x 64)^T
#pragma unroll
    for (int ks = 0; ks < 2; ++ks) {
      short8 pa[4], vb[4];
#pragma unroll
      for (int m = 0; m < 4; ++m) {
        int row = wr * 64 + m * 16 + (lane & 15);
        int p = (ks * 4 + (lane >> 4)) ^ (row & 7);
        pa[m] = *(const short8*)(&Ps[row * 64 + p * 8]);
      }
#pragma unroll
      for (int nn = 0; nn < 4; ++nn) {
        int row = wc * 64 + nn * 16 + (lane & 15);
        int p = (ks * 4 + (lane >> 4)) ^ (row & 7);
        vb[nn] = *(const short8*)(&Vs[row * 64 + p * 8]);
      }
#pragma unroll
      for (int m = 0; m < 4; ++m)
#pragma unroll
        for (int nn = 0; nn < 4; ++nn)
          acco[m][nn] = __builtin_amdgcn_mfma_f32_16x16x32_bf16(pa[m], vb[nn], acco[m][nn], 0, 0, 0);
    }
  }

  // ---- epilogue: context (normalized) bf16, permuted layout ----
#pragma unroll
  for (int m = 0; m < 4; ++m) {
#pragma unroll
    for (int nn = 0; nn < 4; ++nn) {
#pragma unroll
      for (int j = 0; j < 4; ++j) {
        int row = wr * 64 + m * 16 + ((lane >> 4) * 4) + j;   // s in tile
        int col = wc * 64 + nn * 16 + (lane & 15);            // dk
        Cb[((long)(n >> 4) * Sc + m0 + row) * (long)Dc + (long)(n & 15) * DKc + col] =
            (ushort_t)f2bf(acco[m][nn][j]);
      }
    }
  }
}

// ---------------------------------------------------------------------------
__global__ __launch_bounds__(256)
void cast_bf16(const float* __restrict__ in, ushort_t* __restrict__ out) {
  long i = ((long)blockIdx.x * 256 + threadIdx.x) * 8;
  f32x4 a = *(const f32x4*)(in + i);
  f32x4 b = *(const f32x4*)(in + i + 4);
  *(short8*)(out + i) = pack8(a, b);
}

// in-place row layernorm on (8192, 2048) fp32
__global__ __launch_bounds__(256)
void layernorm_rows(float* __restrict__ out, const float* __restrict__ gamma,
                    const float* __restrict__ beta) {
  const long row = blockIdx.x;
  float* p = out + row * (long)Dc;
  const int tid = threadIdx.x;
  const int lane = tid & 63, wave = tid >> 6;
  f32x4 v0 = *(const f32x4*)(p + tid * 8);
  f32x4 v1 = *(const f32x4*)(p + tid * 8 + 4);
  float s = 0.f, ss = 0.f;
#pragma unroll
  for (int e = 0; e < 4; ++e) { s += v0[e]; ss += v0[e] * v0[e]; }
#pragma unroll
  for (int e = 0; e < 4; ++e) { s += v1[e]; ss += v1[e] * v1[e]; }
  for (int off = 32; off > 0; off >>= 1) { s += __shfl_xor(s, off); ss += __shfl_xor(ss, off); }
  __shared__ float rs_[4], rss_[4];
  if (lane == 0) { rs_[wave] = s; rss_[wave] = ss; }
  __syncthreads();
  s  = rs_[0] + rs_[1] + rs_[2] + rs_[3];
  ss = rss_[0] + rss_[1] + rss_[2] + rss_[3];
  const float mean = s * (1.f / Dc);
  const float var  = ss * (1.f / Dc) - mean * mean;
  const float rstd = rsqrtf(var + 1e-6f);
  f32x4 g0 = *(const f32x4*)(gamma + tid * 8);
  f32x4 g1 = *(const f32x4*)(gamma + tid * 8 + 4);
  f32x4 b0 = *(const f32x4*)(beta + tid * 8);
  f32x4 b1 = *(const f32x4*)(beta + tid * 8 + 4);
#pragma unroll
  for (int e = 0; e < 4; ++e) v0[e] = (v0[e] - mean) * rstd * g0[e] + b0[e];
#pragma unroll
  for (int e = 0; e < 4; ++e) v1[e] = (v1[e] - mean) * rstd * g1[e] + b1[e];
  *(f32x4*)(p + tid * 8) = v0;
  *(f32x4*)(p + tid * 8 + 4) = v1;
}

// ---------------------------------------------------------------------------
extern "C" void kernel_launch(void* const* d_in, const int* in_sizes, int n_in,
                              void* d_out, int out_size, void* d_ws, size_t ws_size,
                              hipStream_t stream) {
  (void)in_sizes; (void)n_in; (void)out_size; (void)ws_size;
  const float* q  = (const float*)d_in[0];
  const float* k  = (const float*)d_in[1];
  const float* v  = (const float*)d_in[2];
  const float* Wq = (const float*)d_in[3];
  const float* Wk = (const float*)d_in[4];
  const float* Wv = (const float*)d_in[5];
  const float* Wo = (const float*)d_in[6];
  const float* gamma = (const float*)d_in[7];
  const float* beta  = (const float*)d_in[8];

  float* out  = (float*)d_out;
  float* attn = out + OUT_ELEMS;                // 4.3 GB region (output 1)

  // workspace layout (~168 MB)
  ushort_t* Wqb = (ushort_t*)d_ws;
  ushort_t* Wkb = Wqb + (long)Dc * Dc;
  ushort_t* Wvb = Wkb + (long)Dc * Dc;
  ushort_t* Wob = Wvb + (long)Dc * Dc;
  ushort_t* Qb  = Wob + (long)Dc * Dc;
  ushort_t* Kb  = Qb + OUT_ELEMS;
  ushort_t* VT  = Kb + OUT_ELEMS;
  ushort_t* Cb  = VT + OUT_ELEMS;

  // bf16 copies of q,k,v parked in the attn region (dead before flash writes it)
  ushort_t* qb = (ushort_t*)attn;
  ushort_t* kb = qb + OUT_ELEMS;
  ushort_t* vb = kb + OUT_ELEMS;

  dim3 blk(256);
  cast_bf16<<<OUT_ELEMS / 2048, blk, 0, stream>>>(q, qb);
  cast_bf16<<<OUT_ELEMS / 2048, blk, 0, stream>>>(k, kb);
  cast_bf16<<<OUT_ELEMS / 2048, blk, 0, stream>>>(v, vb);
  cast_bf16<<<(long)Dc * Dc / 2048, blk, 0, stream>>>(Wq, Wqb);
  cast_bf16<<<(long)Dc * Dc / 2048, blk, 0, stream>>>(Wk, Wkb);
  cast_bf16<<<(long)Dc * Dc / 2048, blk, 0, stream>>>(Wv, Wvb);
  cast_bf16<<<(long)Dc * Dc / 2048, blk, 0, stream>>>(Wo, Wob);

  // projections
  gemm_nt<0><<<dim3(16, 64, 1), blk, 0, stream>>>(qb, Wqb, Qb, nullptr);
  gemm_nt<0><<<dim3(16, 64, 1), blk, 0, stream>>>(kb, Wkb, Kb, nullptr);
  gemm_nt<1><<<dim3(16, 64, 1), blk, 0, stream>>>(vb, Wvb, VT, nullptr);

  // flash attention: writes normalized fp32 attn + bf16 context
  flash_attn<<<dim3(1024), blk, 0, stream>>>(Qb, Kb, VT, attn, Cb);

  // output projection + residual
  gemm_nt<3><<<dim3(16, 64, 1), blk, 0, stream>>>(Cb, Wob, out, q);

  // layernorm in place
  layernorm_rows<<<NTOK, blk, 0, stream>>>(out, gamma, beta);
}

// Round 4
// 910.667 us; speedup vs baseline: 1.6768x; 1.0699x over previous
//
#include <hip/hip_runtime.h>
#include <cstdint>

typedef __attribute__((ext_vector_type(8))) short short8;
typedef __attribute__((ext_vector_type(4))) float f32x4;
typedef unsigned short ushort_t;

constexpr int Bc = 4, Sc = 2048, Dc = 2048, Hc = 16, DKc = 128;
constexpr long NTOK = (long)Bc * Sc;          // 8192 rows
constexpr long OUT_ELEMS = NTOK * (long)Dc;   // 16777216
constexpr float SCALE = 0.08838834764831843f; // 1/sqrt(128)

__device__ __forceinline__ ushort_t f2bf(float f) {
  unsigned u = __builtin_bit_cast(unsigned, f);
  u = (u + 0x7FFFu + ((u >> 16) & 1u)) >> 16;
  return (ushort_t)u;
}

__device__ __forceinline__ short8 pack8(const f32x4& a, const f32x4& b) {
  short8 h;
  h[0] = (short)f2bf(a[0]); h[1] = (short)f2bf(a[1]);
  h[2] = (short)f2bf(a[2]); h[3] = (short)f2bf(a[3]);
  h[4] = (short)f2bf(b[0]); h[5] = (short)f2bf(b[1]);
  h[6] = (short)f2bf(b[2]); h[7] = (short)f2bf(b[3]);
  return h;
}

// async global->LDS, 16B per lane; lds dest is wave-uniform base + lane*16
__device__ __forceinline__ void gl2lds16(const ushort_t* g, ushort_t* l) {
  __builtin_amdgcn_global_load_lds(
      (__attribute__((address_space(1))) unsigned int*)(g),
      (__attribute__((address_space(3))) unsigned int*)(l), 16, 0, 0);
}

__device__ __forceinline__ void bar() {
  asm volatile("" ::: "memory");
  __builtin_amdgcn_s_barrier();
  asm volatile("" ::: "memory");
}

// ---------------------------------------------------------------------------
// 256x256 8-phase NT GEMM: C = A(Mx2048) * B(2048x2048)^T, BK=64, 512 thr
// (8 waves = 2M x 4N, per-wave output 128x64). Double-buffered 128KB LDS.
// Per K-tile: 4 phases (quadrants). Counted vmcnt(4) once per K-tile.
// Prefetch: B1/A1(kt+1) issued at kt.P0/P1 (buf^1); B0/A0(kt+2) at kt.P2/P3
// (cur parity, after those regions' last reads at kt.P0/P1). Tail wraps.
// MODE 0: C bf16 row-major; MODE 1: C=VT transposed bf16; MODE 3: fp32+residual
// ---------------------------------------------------------------------------
template<int MODE>
__global__ __launch_bounds__(512, 2)
void gemm256(const ushort_t* __restrict__ Ap, const ushort_t* __restrict__ Bp,
             void* __restrict__ Cp, const float* __restrict__ residual)
{
  __shared__ __align__(16) ushort_t As[2][2][128 * 64]; // [buf][half][row*64+col]
  __shared__ __align__(16) ushort_t Bs[2][2][128 * 64];

  const int tid = threadIdx.x, lane = tid & 63, wave = tid >> 6;
  const int wm = wave >> 2, wn = wave & 3;

  // bijective XCD swizzle over 256 blocks, grid (8, 32)
  const int lin = blockIdx.y * 8 + blockIdx.x;
  const int swz = (lin & 7) * 32 + (lin >> 3);
  const long n0 = (long)(swz & 7) * 256;
  const long m0 = (long)(swz >> 3) * 256;

  constexpr int NT = 32; // K=2048 / 64

  const ushort_t* Ag = Ap + m0 * (long)Dc;
  const ushort_t* Bg = Bp + n0 * (long)Dc;

  // stage one half-tile (128 rows x 64 cols): 2 gl2lds per wave
  auto stage = [&](const ushort_t* gb, ushort_t* dst, int kt, int ht) {
#pragma unroll
    for (int c = 0; c < 2; ++c) {
      int U = (c * 8 + wave) * 64 + lane;
      int row = U >> 3, p = U & 7, u = p ^ (row & 7);
      gl2lds16(gb + (long)(ht * 128 + row) * Dc + kt * 64 + u * 8,
               dst + (c * 8 + wave) * 512);
    }
  };

  // ---- prologue: B0(0),A0(0),B1(0),A1(0),B0(1),A0(1); wait first 4 ----
  stage(Bg, &Bs[0][0][0], 0, 0);
  stage(Ag, &As[0][0][0], 0, 0);
  stage(Bg, &Bs[0][1][0], 0, 1);
  stage(Ag, &As[0][1][0], 0, 1);
  stage(Bg, &Bs[1][0][0], 1, 0);
  stage(Ag, &As[1][0][0], 1, 0);
  asm volatile("s_waitcnt vmcnt(4)" ::: "memory");
  __builtin_amdgcn_s_barrier();
  asm volatile("" ::: "memory");

  f32x4 acc[8][4] = {};

  for (int kt = 0; kt < NT; ++kt) {
    const int cur = kt & 1;
    const ushort_t* Acur = &As[cur][0][0];
    const ushort_t* Bcur = &Bs[cur][0][0];
    const int k1 = (kt + 1) & (NT - 1);   // wrap at tail (junk into dead buf)
    const int k2 = (kt + 2) & (NT - 1);
    short8 af[4][2], bq0[2][2], bq1[2][2];

    // ======== P0: ds A(mh0) + B(q0); issue B1(kt+1); MFMA q(0,0) ========
#pragma unroll
    for (int mf = 0; mf < 4; ++mf)
#pragma unroll
      for (int ks = 0; ks < 2; ++ks) {
        int r = mf * 16 + (lane & 15);
        int u = ks * 4 + (lane >> 4), p = u ^ (r & 7);
        af[mf][ks] = *(const short8*)(Acur + wm * (128 * 64) + r * 64 + p * 8);
      }
#pragma unroll
    for (int nf = 0; nf < 2; ++nf)
#pragma unroll
      for (int ks = 0; ks < 2; ++ks) {
        int r = (wn & 1) * 64 + nf * 16 + (lane & 15);
        int u = ks * 4 + (lane >> 4), p = u ^ (r & 7);
        bq0[nf][ks] = *(const short8*)(Bcur + (wn >> 1) * (128 * 64) + r * 64 + p * 8);
      }
    stage(Bg, &Bs[cur ^ 1][1][0], k1, 1);
    bar();
    __builtin_amdgcn_s_setprio(1);
#pragma unroll
    for (int mf = 0; mf < 4; ++mf)
#pragma unroll
      for (int nf = 0; nf < 2; ++nf)
#pragma unroll
        for (int ks = 0; ks < 2; ++ks)
          acc[mf][nf] = __builtin_amdgcn_mfma_f32_16x16x32_bf16(af[mf][ks], bq0[nf][ks], acc[mf][nf], 0, 0, 0);
    __builtin_amdgcn_s_setprio(0);
    bar();

    // ======== P1: ds B(q1); issue A1(kt+1); MFMA q(0,1) ========
#pragma unroll
    for (int nf = 0; nf < 2; ++nf)
#pragma unroll
      for (int ks = 0; ks < 2; ++ks) {
        int r = (wn & 1) * 64 + 32 + nf * 16 + (lane & 15);
        int u = ks * 4 + (lane >> 4), p = u ^ (r & 7);
        bq1[nf][ks] = *(const short8*)(Bcur + (wn >> 1) * (128 * 64) + r * 64 + p * 8);
      }
    stage(Ag, &As[cur ^ 1][1][0], k1, 1);
    bar();
    __builtin_amdgcn_s_setprio(1);
#pragma unroll
    for (int mf = 0; mf < 4; ++mf)
#pragma unroll
      for (int nf = 0; nf < 2; ++nf)
#pragma unroll
        for (int ks = 0; ks < 2; ++ks)
          acc[mf][2 + nf] = __builtin_amdgcn_mfma_f32_16x16x32_bf16(af[mf][ks], bq1[nf][ks], acc[mf][2 + nf], 0, 0, 0);
    __builtin_amdgcn_s_setprio(0);
    bar();

    // ======== P2: ds A(mh1); issue B0(kt+2); MFMA q(1,0) ========
#pragma unroll
    for (int mf = 0; mf < 4; ++mf)
#pragma unroll
      for (int ks = 0; ks < 2; ++ks) {
        int r = 64 + mf * 16 + (lane & 15);
        int u = ks * 4 + (lane >> 4), p = u ^ (r & 7);
        af[mf][ks] = *(const short8*)(Acur + wm * (128 * 64) + r * 64 + p * 8);
      }
    stage(Bg, &Bs[cur][0][0], k2, 0);
    bar();
    __builtin_amdgcn_s_setprio(1);
#pragma unroll
    for (int mf = 0; mf < 4; ++mf)
#pragma unroll
      for (int nf = 0; nf < 2; ++nf)
#pragma unroll
        for (int ks = 0; ks < 2; ++ks)
          acc[4 + mf][nf] = __builtin_amdgcn_mfma_f32_16x16x32_bf16(af[mf][ks], bq0[nf][ks], acc[4 + mf][nf], 0, 0, 0);
    __builtin_amdgcn_s_setprio(0);
    bar();

    // ======== P3: issue A0(kt+2); vmcnt(4); MFMA q(1,1) ========
    stage(Ag, &As[cur][0][0], k2, 0);
    asm volatile("s_waitcnt vmcnt(4)" ::: "memory");
    bar();
    __builtin_amdgcn_s_setprio(1);
#pragma unroll
    for (int mf = 0; mf < 4; ++mf)
#pragma unroll
      for (int nf = 0; nf < 2; ++nf)
#pragma unroll
        for (int ks = 0; ks < 2; ++ks)
          acc[4 + mf][2 + nf] = __builtin_amdgcn_mfma_f32_16x16x32_bf16(af[mf][ks], bq1[nf][ks], acc[4 + mf][2 + nf], 0, 0, 0);
    __builtin_amdgcn_s_setprio(0);
    bar();
  }

  asm volatile("s_waitcnt vmcnt(0)" ::: "memory");

  // ---- epilogue: frag (mq,nq): row = m0+wm*128+(mq/4)*64+(mq%4)*16+(lane>>4)*4+j
  //                              col = n0+wn*64+(nq/2)*32+(nq%2)*16+(lane&15)
#pragma unroll
  for (int mq = 0; mq < 8; ++mq) {
#pragma unroll
    for (int nq = 0; nq < 4; ++nq) {
#pragma unroll
      for (int j = 0; j < 4; ++j) {
        long rg = m0 + wm * 128 + (mq >> 2) * 64 + (mq & 3) * 16 + ((lane >> 4) * 4) + j;
        long cg = n0 + wn * 64 + (nq >> 1) * 32 + (nq & 1) * 16 + (lane & 15);
        float val = acc[mq][nq][j];
        if constexpr (MODE == 0) {
          ((ushort_t*)Cp)[rg * (long)Dc + cg] = f2bf(val);
        } else if constexpr (MODE == 1) {
          long b = rg >> 11, s = rg & 2047;   // rg over B*S, S=2048
          long h = cg >> 7,  dk = cg & 127;   // cg over D
          ((ushort_t*)Cp)[((h * 4 + b) * 128 + dk) * (long)Sc + s] = f2bf(val);
        } else if constexpr (MODE == 3) {
          ((float*)Cp)[rg * (long)Dc + cg] = val + residual[rg * (long)Dc + cg];
        }
      }
    }
  }
}

// ---------------------------------------------------------------------------
// Flash attention: one block per (n=h*4+b, m-tile of 128 q-rows).
// Loop A: rowsums of exp(QK^T*scale). Loop B: recompute, write normalized
// fp32 P to attn (only attn write), PV accumulate via LDS bf16 P.
// LDS: Qs 32K + Ks 16K + Vs 16K + Ps 16K = 80KB -> 2 blocks/CU.
// ---------------------------------------------------------------------------
__global__ __launch_bounds__(256, 2)
void flash_attn(const ushort_t* __restrict__ Qb, const ushort_t* __restrict__ Kb,
                const ushort_t* __restrict__ VT, float* __restrict__ attn,
                ushort_t* __restrict__ Cb)
{
  __shared__ __align__(16) ushort_t Qs[128 * 128]; // swz u^(row&15)
  __shared__ __align__(16) ushort_t Ks[64 * 128];  // swz u^(row&15)
  __shared__ __align__(16) ushort_t Vs[128 * 64];  // swz u^(row&7)
  __shared__ __align__(16) ushort_t Ps[128 * 64];  // swz u^(row&7)

  const int tid = threadIdx.x, lane = tid & 63, wave = tid >> 6;
  const int wr = wave >> 1, wc = wave & 1;

  const int bid = blockIdx.x;
  const int xcd = bid & 7, slot = bid >> 3;
  const int n = xcd * 8 + (slot >> 4);
  const long m0 = (long)(slot & 15) * 128;
  const int b = n & 3, h = n >> 2;

  const ushort_t* Qg = Qb + ((long)b * Sc) * Dc + (long)h * DKc;
  const ushort_t* Kg = Kb + ((long)b * Sc) * Dc + (long)h * DKc;
  const ushort_t* Vg = VT + (long)n * DKc * (long)Sc;
  float* Pg = attn + (long)n * Sc * (long)Sc;

#pragma unroll
  for (int c8 = 0; c8 < 8; ++c8) {
    int chunk = c8 * 4 + wave;
    int U = chunk * 64 + lane;
    int row = U >> 4, p = U & 15, u = p ^ (row & 15);
    gl2lds16(Qg + (m0 + row) * (long)Dc + u * 8, &Qs[chunk * 512]);
  }

  float rs[4][4] = {};

  for (int t = 0; t < 32; ++t) {
    __syncthreads();
#pragma unroll
    for (int c4 = 0; c4 < 4; ++c4) {
      int chunk = c4 * 4 + wave;
      int U = chunk * 64 + lane;
      int row = U >> 4, p = U & 15, u = p ^ (row & 15);
      gl2lds16(Kg + ((long)t * 64 + row) * (long)Dc + u * 8, &Ks[chunk * 512]);
    }
    __syncthreads();
    f32x4 acc[4][2] = {};
#pragma unroll
    for (int kk = 0; kk < 4; ++kk) {
      short8 af[4], bfr[2];
#pragma unroll
      for (int m = 0; m < 4; ++m) {
        int row = wr * 64 + m * 16 + (lane & 15);
        int p = (kk * 4 + (lane >> 4)) ^ (row & 15);
        af[m] = *(const short8*)(&Qs[row * 128 + p * 8]);
      }
#pragma unroll
      for (int nn = 0; nn < 2; ++nn) {
        int row = wc * 32 + nn * 16 + (lane & 15);
        int p = (kk * 4 + (lane >> 4)) ^ (row & 15);
        bfr[nn] = *(const short8*)(&Ks[row * 128 + p * 8]);
      }
#pragma unroll
      for (int m = 0; m < 4; ++m)
#pragma unroll
        for (int nn = 0; nn < 2; ++nn)
          acc[m][nn] = __builtin_amdgcn_mfma_f32_16x16x32_bf16(af[m], bfr[nn], acc[m][nn], 0, 0, 0);
    }
#pragma unroll
    for (int m = 0; m < 4; ++m)
#pragma unroll
      for (int nn = 0; nn < 2; ++nn)
#pragma unroll
        for (int j = 0; j < 4; ++j)
          rs[m][j] += __expf(acc[m][nn][j] * SCALE);
  }

  float* red = (float*)Ps;
#pragma unroll
  for (int m = 0; m < 4; ++m)
#pragma unroll
    for (int j = 0; j < 4; ++j) {
#pragma unroll
      for (int off = 1; off < 16; off <<= 1)
        rs[m][j] += __shfl_xor(rs[m][j], off);
    }
  if ((lane & 15) == 0) {
#pragma unroll
    for (int m = 0; m < 4; ++m)
#pragma unroll
      for (int j = 0; j < 4; ++j)
        red[wc * 128 + wr * 64 + m * 16 + ((lane >> 4) * 4) + j] = rs[m][j];
  }
  __syncthreads();
  float invl[4][4];
#pragma unroll
  for (int m = 0; m < 4; ++m)
#pragma unroll
    for (int j = 0; j < 4; ++j) {
      int row = wr * 64 + m * 16 + ((lane >> 4) * 4) + j;
      invl[m][j] = 1.f / (red[row] + red[128 + row]);
    }
  __syncthreads();

  f32x4 acco[4][4] = {};
  for (int t = 0; t < 32; ++t) {
    __syncthreads();
#pragma unroll
    for (int c4 = 0; c4 < 4; ++c4) {
      int chunk = c4 * 4 + wave;
      int U = chunk * 64 + lane;
      int row = U >> 4, p = U & 15, u = p ^ (row & 15);
      gl2lds16(Kg + ((long)t * 64 + row) * (long)Dc + u * 8, &Ks[chunk * 512]);
    }
#pragma unroll
    for (int c4 = 0; c4 < 4; ++c4) {
      int chunk = c4 * 4 + wave;
      int U = chunk * 64 + lane;
      int row = U >> 3, p = U & 7, u = p ^ (row & 7);
      gl2lds16(Vg + (long)row * Sc + (long)t * 64 + u * 8, &Vs[chunk * 512]);
    }
    __syncthreads();
    f32x4 acc[4][2] = {};
#pragma unroll
    for (int kk = 0; kk < 4; ++kk) {
      short8 af[4], bfr[2];
#pragma unroll
      for (int m = 0; m < 4; ++m) {
        int row = wr * 64 + m * 16 + (lane & 15);
        int p = (kk * 4 + (lane >> 4)) ^ (row & 15);
        af[m] = *(const short8*)(&Qs[row * 128 + p * 8]);
      }
#pragma unroll
      for (int nn = 0; nn < 2; ++nn) {
        int row = wc * 32 + nn * 16 + (lane & 15);
        int p = (kk * 4 + (lane >> 4)) ^ (row & 15);
        bfr[nn] = *(const short8*)(&Ks[row * 128 + p * 8]);
      }
#pragma unroll
      for (int m = 0; m < 4; ++m)
#pragma unroll
        for (int nn = 0; nn < 2; ++nn)
          acc[m][nn] = __builtin_amdgcn_mfma_f32_16x16x32_bf16(af[m], bfr[nn], acc[m][nn], 0, 0, 0);
    }
#pragma unroll
    for (int m = 0; m < 4; ++m) {
#pragma unroll
      for (int nn = 0; nn < 2; ++nn) {
#pragma unroll
        for (int j = 0; j < 4; ++j) {
          float e = __expf(acc[m][nn][j] * SCALE) * invl[m][j];
          int row = wr * 64 + m * 16 + ((lane >> 4) * 4) + j;
          int col = wc * 32 + nn * 16 + (lane & 15);
          Pg[(m0 + row) * (long)Sc + (long)t * 64 + col] = e;
          int pp = (col >> 3) ^ (row & 7);
          Ps[row * 64 + pp * 8 + (col & 7)] = (ushort_t)f2bf(e);
        }
      }
    }
    __syncthreads();
#pragma unroll
    for (int ks = 0; ks < 2; ++ks) {
      short8 pa[4], vb[4];
#pragma unroll
      for (int m = 0; m < 4; ++m) {
        int row = wr * 64 + m * 16 + (lane & 15);
        int p = (ks * 4 + (lane >> 4)) ^ (row & 7);
        pa[m] = *(const short8*)(&Ps[row * 64 + p * 8]);
      }
#pragma unroll
      for (int nn = 0; nn < 4; ++nn) {
        int row = wc * 64 + nn * 16 + (lane & 15);
        int p = (ks * 4 + (lane >> 4)) ^ (row & 7);
        vb[nn] = *(const short8*)(&Vs[row * 64 + p * 8]);
      }
#pragma unroll
      for (int m = 0; m < 4; ++m)
#pragma unroll
        for (int nn = 0; nn < 4; ++nn)
          acco[m][nn] = __builtin_amdgcn_mfma_f32_16x16x32_bf16(pa[m], vb[nn], acco[m][nn], 0, 0, 0);
    }
  }

#pragma unroll
  for (int m = 0; m < 4; ++m) {
#pragma unroll
    for (int nn = 0; nn < 4; ++nn) {
#pragma unroll
      for (int j = 0; j < 4; ++j) {
        int row = wr * 64 + m * 16 + ((lane >> 4) * 4) + j;
        int col = wc * 64 + nn * 16 + (lane & 15);
        Cb[((long)(n >> 4) * Sc + m0 + row) * (long)Dc + (long)(n & 15) * DKc + col] =
            (ushort_t)f2bf(acco[m][nn][j]);
      }
    }
  }
}

// ---------------------------------------------------------------------------
__global__ __launch_bounds__(256)
void cast_bf16(const float* __restrict__ in, ushort_t* __restrict__ out) {
  long i = ((long)blockIdx.x * 256 + threadIdx.x) * 8;
  f32x4 a = *(const f32x4*)(in + i);
  f32x4 b = *(const f32x4*)(in + i + 4);
  *(short8*)(out + i) = pack8(a, b);
}

// in-place row layernorm on (8192, 2048) fp32
__global__ __launch_bounds__(256)
void layernorm_rows(float* __restrict__ out, const float* __restrict__ gamma,
                    const float* __restrict__ beta) {
  const long row = blockIdx.x;
  float* p = out + row * (long)Dc;
  const int tid = threadIdx.x;
  const int lane = tid & 63, wave = tid >> 6;
  f32x4 v0 = *(const f32x4*)(p + tid * 8);
  f32x4 v1 = *(const f32x4*)(p + tid * 8 + 4);
  float s = 0.f, ss = 0.f;
#pragma unroll
  for (int e = 0; e < 4; ++e) { s += v0[e]; ss += v0[e] * v0[e]; }
#pragma unroll
  for (int e = 0; e < 4; ++e) { s += v1[e]; ss += v1[e] * v1[e]; }
  for (int off = 32; off > 0; off >>= 1) { s += __shfl_xor(s, off); ss += __shfl_xor(ss, off); }
  __shared__ float rs_[4], rss_[4];
  if (lane == 0) { rs_[wave] = s; rss_[wave] = ss; }
  __syncthreads();
  s  = rs_[0] + rs_[1] + rs_[2] + rs_[3];
  ss = rss_[0] + rss_[1] + rss_[2] + rss_[3];
  const float mean = s * (1.f / Dc);
  const float var  = ss * (1.f / Dc) - mean * mean;
  const float rstd = rsqrtf(var + 1e-6f);
  f32x4 g0 = *(const f32x4*)(gamma + tid * 8);
  f32x4 g1 = *(const f32x4*)(gamma + tid * 8 + 4);
  f32x4 b0 = *(const f32x4*)(beta + tid * 8);
  f32x4 b1 = *(const f32x4*)(beta + tid * 8 + 4);
#pragma unroll
  for (int e = 0; e < 4; ++e) v0[e] = (v0[e] - mean) * rstd * g0[e] + b0[e];
#pragma unroll
  for (int e = 0; e < 4; ++e) v1[e] = (v1[e] - mean) * rstd * g1[e] + b1[e];
  *(f32x4*)(p + tid * 8) = v0;
  *(f32x4*)(p + tid * 8 + 4) = v1;
}

// ---------------------------------------------------------------------------
extern "C" void kernel_launch(void* const* d_in, const int* in_sizes, int n_in,
                              void* d_out, int out_size, void* d_ws, size_t ws_size,
                              hipStream_t stream) {
  (void)in_sizes; (void)n_in; (void)out_size; (void)ws_size;
  const float* q  = (const float*)d_in[0];
  const float* k  = (const float*)d_in[1];
  const float* v  = (const float*)d_in[2];
  const float* Wq = (const float*)d_in[3];
  const float* Wk = (const float*)d_in[4];
  const float* Wv = (const float*)d_in[5];
  const float* Wo = (const float*)d_in[6];
  const float* gamma = (const float*)d_in[7];
  const float* beta  = (const float*)d_in[8];

  float* out  = (float*)d_out;
  float* attn = out + OUT_ELEMS;                // 4.3 GB region (output 1)

  // workspace layout (~168 MB)
  ushort_t* Wqb = (ushort_t*)d_ws;
  ushort_t* Wkb = Wqb + (long)Dc * Dc;
  ushort_t* Wvb = Wkb + (long)Dc * Dc;
  ushort_t* Wob = Wvb + (long)Dc * Dc;
  ushort_t* Qb  = Wob + (long)Dc * Dc;
  ushort_t* Kb  = Qb + OUT_ELEMS;
  ushort_t* VT  = Kb + OUT_ELEMS;
  ushort_t* Cb  = VT + OUT_ELEMS;

  // bf16 copies of q,k,v parked in the attn region (dead before flash writes it)
  ushort_t* qb = (ushort_t*)attn;
  ushort_t* kb = qb + OUT_ELEMS;
  ushort_t* vb = kb + OUT_ELEMS;

  dim3 blk(256);
  cast_bf16<<<OUT_ELEMS / 2048, blk, 0, stream>>>(q, qb);
  cast_bf16<<<OUT_ELEMS / 2048, blk, 0, stream>>>(k, kb);
  cast_bf16<<<OUT_ELEMS / 2048, blk, 0, stream>>>(v, vb);
  cast_bf16<<<(long)Dc * Dc / 2048, blk, 0, stream>>>(Wq, Wqb);
  cast_bf16<<<(long)Dc * Dc / 2048, blk, 0, stream>>>(Wk, Wkb);
  cast_bf16<<<(long)Dc * Dc / 2048, blk, 0, stream>>>(Wv, Wvb);
  cast_bf16<<<(long)Dc * Dc / 2048, blk, 0, stream>>>(Wo, Wob);

  // projections (256x256 tiles, grid 8x32)
  gemm256<0><<<dim3(8, 32), dim3(512), 0, stream>>>(qb, Wqb, Qb, nullptr);
  gemm256<0><<<dim3(8, 32), dim3(512), 0, stream>>>(kb, Wkb, Kb, nullptr);
  gemm256<1><<<dim3(8, 32), dim3(512), 0, stream>>>(vb, Wvb, VT, nullptr);

  // flash attention: writes normalized fp32 attn + bf16 context
  flash_attn<<<dim3(1024), blk, 0, stream>>>(Qb, Kb, VT, attn, Cb);

  // output projection + residual
  gemm256<3><<<dim3(8, 32), dim3(512), 0, stream>>>(Cb, Wob, out, q);

  // layernorm in place
  layernorm_rows<<<NTOK, blk, 0, stream>>>(out, gamma, beta);
}

// Round 5
// 765.307 us; speedup vs baseline: 1.9953x; 1.1899x over previous
//
#include <hip/hip_runtime.h>
#include <cstdint>

typedef __attribute__((ext_vector_type(8))) short short8;
typedef __attribute__((ext_vector_type(4))) float f32x4;
typedef __attribute__((ext_vector_type(2))) unsigned u32x2;
typedef unsigned short ushort_t;

constexpr int Bc = 4, Sc = 2048, Dc = 2048, Hc = 16, DKc = 128;
constexpr long NTOK = (long)Bc * Sc;          // 8192 rows
constexpr long OUT_ELEMS = NTOK * (long)Dc;   // 16777216
constexpr float SCALE = 0.08838834764831843f; // 1/sqrt(128)

__device__ __forceinline__ ushort_t f2bf(float f) {
  unsigned u = __builtin_bit_cast(unsigned, f);
  u = (u + 0x7FFFu + ((u >> 16) & 1u)) >> 16;
  return (ushort_t)u;
}

__device__ __forceinline__ short8 pack8(const f32x4& a, const f32x4& b) {
  short8 h;
  h[0] = (short)f2bf(a[0]); h[1] = (short)f2bf(a[1]);
  h[2] = (short)f2bf(a[2]); h[3] = (short)f2bf(a[3]);
  h[4] = (short)f2bf(b[0]); h[5] = (short)f2bf(b[1]);
  h[6] = (short)f2bf(b[2]); h[7] = (short)f2bf(b[3]);
  return h;
}

// async global->LDS, 16B per lane; lds dest is wave-uniform base + lane*16
__device__ __forceinline__ void gl2lds16(const ushort_t* g, ushort_t* l) {
  __builtin_amdgcn_global_load_lds(
      (__attribute__((address_space(1))) unsigned int*)(g),
      (__attribute__((address_space(3))) unsigned int*)(l), 16, 0, 0);
}

__device__ __forceinline__ void bar() {
  asm volatile("" ::: "memory");
  __builtin_amdgcn_s_barrier();
  asm volatile("" ::: "memory");
}

// ---------------------------------------------------------------------------
// 256x256 8-phase NT GEMM: C = A(Mx2048) * B(2048x2048)^T, BK=64, 512 thr
// (8 waves = 2M x 4N). Double-buffered 128KB LDS, counted vmcnt(4)/K-tile.
// MODE 0: C bf16 row-major; MODE 1: C=VT transposed bf16 (LDS-transpose
// epilogue, coalesced 16B stores); MODE 3: fp32 + residual.
// ---------------------------------------------------------------------------
template<int MODE>
__global__ __launch_bounds__(512, 2)
void gemm256(const ushort_t* __restrict__ Ap, const ushort_t* __restrict__ Bp,
             void* __restrict__ Cp, const float* __restrict__ residual)
{
  __shared__ __align__(16) ushort_t SM[2][2][2][128 * 64]; // [A/B][buf][half]

  const int tid = threadIdx.x, lane = tid & 63, wave = tid >> 6;
  const int wm = wave >> 2, wn = wave & 3;

  // bijective XCD swizzle over 256 blocks, grid (8, 32)
  const int lin = blockIdx.y * 8 + blockIdx.x;
  const int swz = (lin & 7) * 32 + (lin >> 3);
  const long n0 = (long)(swz & 7) * 256;
  const long m0 = (long)(swz >> 3) * 256;

  constexpr int NT = 32; // K=2048 / 64

  const ushort_t* Ag = Ap + m0 * (long)Dc;
  const ushort_t* Bg = Bp + n0 * (long)Dc;

  // stage one half-tile (128 rows x 64 cols): 2 gl2lds per thread
  auto stage = [&](const ushort_t* gb, ushort_t* dst, int kt, int ht) {
#pragma unroll
    for (int c = 0; c < 2; ++c) {
      int U = (c * 8 + wave) * 64 + lane;
      int row = U >> 3, p = U & 7, u = p ^ (row & 7);
      gl2lds16(gb + (long)(ht * 128 + row) * Dc + kt * 64 + u * 8,
               dst + (c * 8 + wave) * 512);
    }
  };

  // ---- prologue ----
  stage(Bg, &SM[1][0][0][0], 0, 0);
  stage(Ag, &SM[0][0][0][0], 0, 0);
  stage(Bg, &SM[1][0][1][0], 0, 1);
  stage(Ag, &SM[0][0][1][0], 0, 1);
  stage(Bg, &SM[1][1][0][0], 1, 0);
  stage(Ag, &SM[0][1][0][0], 1, 0);
  asm volatile("s_waitcnt vmcnt(4)" ::: "memory");
  __builtin_amdgcn_s_barrier();
  asm volatile("" ::: "memory");

  f32x4 acc[8][4] = {};

  for (int kt = 0; kt < NT; ++kt) {
    const int cur = kt & 1;
    const ushort_t* Acur = &SM[0][cur][0][0];
    const ushort_t* Bcur = &SM[1][cur][0][0];
    const int k1 = (kt + 1) & (NT - 1);
    const int k2 = (kt + 2) & (NT - 1);
    short8 af[4][2], bq0[2][2], bq1[2][2];

    // ======== P0 ========
#pragma unroll
    for (int mf = 0; mf < 4; ++mf)
#pragma unroll
      for (int ks = 0; ks < 2; ++ks) {
        int r = mf * 16 + (lane & 15);
        int u = ks * 4 + (lane >> 4), p = u ^ (r & 7);
        af[mf][ks] = *(const short8*)(Acur + wm * (128 * 64) + r * 64 + p * 8);
      }
#pragma unroll
    for (int nf = 0; nf < 2; ++nf)
#pragma unroll
      for (int ks = 0; ks < 2; ++ks) {
        int r = (wn & 1) * 64 + nf * 16 + (lane & 15);
        int u = ks * 4 + (lane >> 4), p = u ^ (r & 7);
        bq0[nf][ks] = *(const short8*)(Bcur + (wn >> 1) * (128 * 64) + r * 64 + p * 8);
      }
    stage(Bg, &SM[1][cur ^ 1][1][0], k1, 1);
    bar();
    __builtin_amdgcn_s_setprio(1);
#pragma unroll
    for (int mf = 0; mf < 4; ++mf)
#pragma unroll
      for (int nf = 0; nf < 2; ++nf)
#pragma unroll
        for (int ks = 0; ks < 2; ++ks)
          acc[mf][nf] = __builtin_amdgcn_mfma_f32_16x16x32_bf16(af[mf][ks], bq0[nf][ks], acc[mf][nf], 0, 0, 0);
    __builtin_amdgcn_s_setprio(0);
    bar();

    // ======== P1 ========
#pragma unroll
    for (int nf = 0; nf < 2; ++nf)
#pragma unroll
      for (int ks = 0; ks < 2; ++ks) {
        int r = (wn & 1) * 64 + 32 + nf * 16 + (lane & 15);
        int u = ks * 4 + (lane >> 4), p = u ^ (r & 7);
        bq1[nf][ks] = *(const short8*)(Bcur + (wn >> 1) * (128 * 64) + r * 64 + p * 8);
      }
    stage(Ag, &SM[0][cur ^ 1][1][0], k1, 1);
    bar();
    __builtin_amdgcn_s_setprio(1);
#pragma unroll
    for (int mf = 0; mf < 4; ++mf)
#pragma unroll
      for (int nf = 0; nf < 2; ++nf)
#pragma unroll
        for (int ks = 0; ks < 2; ++ks)
          acc[mf][2 + nf] = __builtin_amdgcn_mfma_f32_16x16x32_bf16(af[mf][ks], bq1[nf][ks], acc[mf][2 + nf], 0, 0, 0);
    __builtin_amdgcn_s_setprio(0);
    bar();

    // ======== P2 ========
#pragma unroll
    for (int mf = 0; mf < 4; ++mf)
#pragma unroll
      for (int ks = 0; ks < 2; ++ks) {
        int r = 64 + mf * 16 + (lane & 15);
        int u = ks * 4 + (lane >> 4), p = u ^ (r & 7);
        af[mf][ks] = *(const short8*)(Acur + wm * (128 * 64) + r * 64 + p * 8);
      }
    stage(Bg, &SM[1][cur][0][0], k2, 0);
    bar();
    __builtin_amdgcn_s_setprio(1);
#pragma unroll
    for (int mf = 0; mf < 4; ++mf)
#pragma unroll
      for (int nf = 0; nf < 2; ++nf)
#pragma unroll
        for (int ks = 0; ks < 2; ++ks)
          acc[4 + mf][nf] = __builtin_amdgcn_mfma_f32_16x16x32_bf16(af[mf][ks], bq0[nf][ks], acc[4 + mf][nf], 0, 0, 0);
    __builtin_amdgcn_s_setprio(0);
    bar();

    // ======== P3 ========
    stage(Ag, &SM[0][cur][0][0], k2, 0);
    asm volatile("s_waitcnt vmcnt(4)" ::: "memory");
    bar();
    __builtin_amdgcn_s_setprio(1);
#pragma unroll
    for (int mf = 0; mf < 4; ++mf)
#pragma unroll
      for (int nf = 0; nf < 2; ++nf)
#pragma unroll
        for (int ks = 0; ks < 2; ++ks)
          acc[4 + mf][2 + nf] = __builtin_amdgcn_mfma_f32_16x16x32_bf16(af[mf][ks], bq1[nf][ks], acc[4 + mf][2 + nf], 0, 0, 0);
    __builtin_amdgcn_s_setprio(0);
    bar();
  }

  asm volatile("s_waitcnt vmcnt(0)" ::: "memory");

  if constexpr (MODE == 1) {
    // ---- LDS-transpose epilogue: coalesced VT stores ----
    bar();  // all wrapped prefetch gl2lds landed; safe to reuse SM as scratch
    char* Tb = (char*)&SM[0][0][0][0];    // 256 rows(cg) x 512B(rg), XOR-swz
#pragma unroll
    for (int mq = 0; mq < 8; ++mq) {
#pragma unroll
      for (int nq = 0; nq < 4; ++nq) {
        int rg = wm * 128 + (mq >> 2) * 64 + (mq & 3) * 16 + ((lane >> 4) * 4);
        int cg = wn * 64 + (nq >> 1) * 32 + (nq & 1) * 16 + (lane & 15);
        u32x2 t;
        t[0] = (unsigned)f2bf(acc[mq][nq][0]) | ((unsigned)f2bf(acc[mq][nq][1]) << 16);
        t[1] = (unsigned)f2bf(acc[mq][nq][2]) | ((unsigned)f2bf(acc[mq][nq][3]) << 16);
        int off = cg * 512 + (((rg >> 3) ^ (cg & 31)) * 16) + (rg & 7) * 2;
        *(u32x2*)(Tb + off) = t;
      }
    }
    bar();
    const long bq = m0 >> 11;       // batch index (m0 256-aligned within one b)
    const long s0 = m0 & 2047;
#pragma unroll
    for (int i = 0; i < 16; ++i) {
      int row = i * 16 + (tid >> 5);     // cg local 0..255
      int un  = tid & 31;                // 16B unit along rg
      int p = un ^ (row & 31);
      short8 val = *(const short8*)(Tb + row * 512 + p * 16);
      long cgg = n0 + row;
      long vtrow = ((cgg >> 7) * 4 + bq) * 128 + (cgg & 127);
      *(short8*)(&((ushort_t*)Cp)[vtrow * (long)Sc + s0 + un * 8]) = val;
    }
  } else {
#pragma unroll
    for (int mq = 0; mq < 8; ++mq) {
#pragma unroll
      for (int nq = 0; nq < 4; ++nq) {
#pragma unroll
        for (int j = 0; j < 4; ++j) {
          long rg = m0 + wm * 128 + (mq >> 2) * 64 + (mq & 3) * 16 + ((lane >> 4) * 4) + j;
          long cg = n0 + wn * 64 + (nq >> 1) * 32 + (nq & 1) * 16 + (lane & 15);
          float val = acc[mq][nq][j];
          if constexpr (MODE == 0) {
            ((ushort_t*)Cp)[rg * (long)Dc + cg] = f2bf(val);
          } else if constexpr (MODE == 3) {
            ((float*)Cp)[rg * (long)Dc + cg] = val + residual[rg * (long)Dc + cg];
          }
        }
      }
    }
  }
}

// ---------------------------------------------------------------------------
// Flash attention, T14 reg-staged pipeline. One block per (n, 128-row m-tile).
// Loop A: rowsums of exp(QK^T*scale); Loop B: recompute, write normalized
// fp32 P to attn, PV accumulate. K/V loads for t+1 issued at t's top.
// LDS: Qs 32K + Ks 16K + Vs 16K + Ps 16K = 80KB -> 2 blocks/CU.
// ---------------------------------------------------------------------------
__global__ __launch_bounds__(256, 2)
void flash_attn(const ushort_t* __restrict__ Qb, const ushort_t* __restrict__ Kb,
                const ushort_t* __restrict__ VT, float* __restrict__ attn,
                ushort_t* __restrict__ Cb)
{
  __shared__ __align__(16) ushort_t Qs[128 * 128]; // swz u^(row&15)
  __shared__ __align__(16) ushort_t Ks[64 * 128];  // swz u^(row&15)
  __shared__ __align__(16) ushort_t Vs[128 * 64];  // swz u^(row&7)
  __shared__ __align__(16) ushort_t Ps[128 * 64];  // swz u^(row&7)

  const int tid = threadIdx.x, lane = tid & 63, wave = tid >> 6;
  const int wr = wave >> 1, wc = wave & 1;

  const int bid = blockIdx.x;
  const int xcd = bid & 7, slot = bid >> 3;
  const int n = xcd * 8 + (slot >> 4);
  const long m0 = (long)(slot & 15) * 128;
  const int b = n & 3, h = n >> 2;

  const ushort_t* Qg = Qb + ((long)b * Sc) * Dc + (long)h * DKc;
  const ushort_t* Kg = Kb + ((long)b * Sc) * Dc + (long)h * DKc;
  const ushort_t* Vg = VT + (long)n * DKc * (long)Sc;
  float* Pg = attn + (long)n * Sc * (long)Sc;

  // ---- stage Q tile once (gl2lds; drained by first barrier) ----
#pragma unroll
  for (int c8 = 0; c8 < 8; ++c8) {
    int chunk = c8 * 4 + wave;
    int U = chunk * 64 + lane;
    int row = U >> 4, p = U & 15, u = p ^ (row & 15);
    gl2lds16(Qg + (m0 + row) * (long)Dc + u * 8, &Qs[chunk * 512]);
  }

  // K-load address helper (pre-swizzled source -> linear-equivalent content)
  auto kaddr = [&](int t, int c4) -> const short8* {
    int chunk = c4 * 4 + wave;
    int U = chunk * 64 + lane;
    int row = U >> 4, p = U & 15, u = p ^ (row & 15);
    return (const short8*)(Kg + ((long)t * 64 + row) * (long)Dc + u * 8);
  };
  auto vaddr = [&](int t, int c4) -> const short8* {
    int chunk = c4 * 4 + wave;
    int U = chunk * 64 + lane;
    int row = U >> 3, p = U & 7, u = p ^ (row & 7);
    return (const short8*)(Vg + (long)row * Sc + (long)t * 64 + u * 8);
  };

  float rs[4][4] = {};

  // ---- Loop A ----
  short8 kr0 = *kaddr(0, 0), kr1 = *kaddr(0, 1), kr2_ = *kaddr(0, 2), kr3 = *kaddr(0, 3);
  for (int t = 0; t < 32; ++t) {
    __syncthreads();   // prior QK done reading Ks (t=0: no-op)
    *(short8*)(&Ks[(0 * 4 + wave) * 512 + lane * 8]) = kr0;
    *(short8*)(&Ks[(1 * 4 + wave) * 512 + lane * 8]) = kr1;
    *(short8*)(&Ks[(2 * 4 + wave) * 512 + lane * 8]) = kr2_;
    *(short8*)(&Ks[(3 * 4 + wave) * 512 + lane * 8]) = kr3;
    {
      int tn = (t + 1) & 31;
      kr0 = *kaddr(tn, 0); kr1 = *kaddr(tn, 1);
      kr2_ = *kaddr(tn, 2); kr3 = *kaddr(tn, 3);
    }
    __syncthreads();
    f32x4 acc[4][2] = {};
#pragma unroll
    for (int kk = 0; kk < 4; ++kk) {
      short8 af[4], bfr[2];
#pragma unroll
      for (int m = 0; m < 4; ++m) {
        int row = wr * 64 + m * 16 + (lane & 15);
        int p = (kk * 4 + (lane >> 4)) ^ (row & 15);
        af[m] = *(const short8*)(&Qs[row * 128 + p * 8]);
      }
#pragma unroll
      for (int nn = 0; nn < 2; ++nn) {
        int row = wc * 32 + nn * 16 + (lane & 15);
        int p = (kk * 4 + (lane >> 4)) ^ (row & 15);
        bfr[nn] = *(const short8*)(&Ks[row * 128 + p * 8]);
      }
#pragma unroll
      for (int m = 0; m < 4; ++m)
#pragma unroll
        for (int nn = 0; nn < 2; ++nn)
          acc[m][nn] = __builtin_amdgcn_mfma_f32_16x16x32_bf16(af[m], bfr[nn], acc[m][nn], 0, 0, 0);
    }
#pragma unroll
    for (int m = 0; m < 4; ++m)
#pragma unroll
      for (int nn = 0; nn < 2; ++nn)
#pragma unroll
        for (int j = 0; j < 4; ++j)
          rs[m][j] += __expf(acc[m][nn][j] * SCALE);
  }

  // Loop B prologue loads issued early (hide under reduction)
  short8 k0 = *kaddr(0, 0), k1_ = *kaddr(0, 1), k2_ = *kaddr(0, 2), k3 = *kaddr(0, 3);
  short8 v0 = *vaddr(0, 0), v1 = *vaddr(0, 1), v2 = *vaddr(0, 2), v3 = *vaddr(0, 3);

  // ---- rowsum reduce -> invl ----
  float* red = (float*)Ps;
#pragma unroll
  for (int m = 0; m < 4; ++m)
#pragma unroll
    for (int j = 0; j < 4; ++j) {
#pragma unroll
      for (int off = 1; off < 16; off <<= 1)
        rs[m][j] += __shfl_xor(rs[m][j], off);
    }
  __syncthreads();   // loop A's last Ks reads done; Ps free
  if ((lane & 15) == 0) {
#pragma unroll
    for (int m = 0; m < 4; ++m)
#pragma unroll
      for (int j = 0; j < 4; ++j)
        red[wc * 128 + wr * 64 + m * 16 + ((lane >> 4) * 4) + j] = rs[m][j];
  }
  __syncthreads();
  float invl[4][4];
#pragma unroll
  for (int m = 0; m < 4; ++m)
#pragma unroll
    for (int j = 0; j < 4; ++j) {
      int row = wr * 64 + m * 16 + ((lane >> 4) * 4) + j;
      invl[m][j] = 1.f / (red[row] + red[128 + row]);
    }

  // ---- Loop B ----
  f32x4 acco[4][4] = {};
  for (int t = 0; t < 32; ++t) {
    __syncthreads();   // prior PV done reading Vs/Ps; invl reads done (t=0)
    *(short8*)(&Ks[(0 * 4 + wave) * 512 + lane * 8]) = k0;
    *(short8*)(&Ks[(1 * 4 + wave) * 512 + lane * 8]) = k1_;
    *(short8*)(&Ks[(2 * 4 + wave) * 512 + lane * 8]) = k2_;
    *(short8*)(&Ks[(3 * 4 + wave) * 512 + lane * 8]) = k3;
    *(short8*)(&Vs[(0 * 4 + wave) * 512 + lane * 8]) = v0;
    *(short8*)(&Vs[(1 * 4 + wave) * 512 + lane * 8]) = v1;
    *(short8*)(&Vs[(2 * 4 + wave) * 512 + lane * 8]) = v2;
    *(short8*)(&Vs[(3 * 4 + wave) * 512 + lane * 8]) = v3;
    {
      int tn = (t + 1) & 31;
      k0 = *kaddr(tn, 0); k1_ = *kaddr(tn, 1); k2_ = *kaddr(tn, 2); k3 = *kaddr(tn, 3);
      v0 = *vaddr(tn, 0); v1 = *vaddr(tn, 1); v2 = *vaddr(tn, 2); v3 = *vaddr(tn, 3);
    }
    __syncthreads();
    f32x4 acc[4][2] = {};
#pragma unroll
    for (int kk = 0; kk < 4; ++kk) {
      short8 af[4], bfr[2];
#pragma unroll
      for (int m = 0; m < 4; ++m) {
        int row = wr * 64 + m * 16 + (lane & 15);
        int p = (kk * 4 + (lane >> 4)) ^ (row & 15);
        af[m] = *(const short8*)(&Qs[row * 128 + p * 8]);
      }
#pragma unroll
      for (int nn = 0; nn < 2; ++nn) {
        int row = wc * 32 + nn * 16 + (lane & 15);
        int p = (kk * 4 + (lane >> 4)) ^ (row & 15);
        bfr[nn] = *(const short8*)(&Ks[row * 128 + p * 8]);
      }
#pragma unroll
      for (int m = 0; m < 4; ++m)
#pragma unroll
        for (int nn = 0; nn < 2; ++nn)
          acc[m][nn] = __builtin_amdgcn_mfma_f32_16x16x32_bf16(af[m], bfr[nn], acc[m][nn], 0, 0, 0);
    }
#pragma unroll
    for (int m = 0; m < 4; ++m) {
#pragma unroll
      for (int nn = 0; nn < 2; ++nn) {
#pragma unroll
        for (int j = 0; j < 4; ++j) {
          float e = __expf(acc[m][nn][j] * SCALE) * invl[m][j];
          int row = wr * 64 + m * 16 + ((lane >> 4) * 4) + j;
          int col = wc * 32 + nn * 16 + (lane & 15);
          Pg[(m0 + row) * (long)Sc + (long)t * 64 + col] = e;
          int pp = (col >> 3) ^ (row & 7);
          Ps[row * 64 + pp * 8 + (col & 7)] = (ushort_t)f2bf(e);
        }
      }
    }
    __syncthreads();
#pragma unroll
    for (int ks = 0; ks < 2; ++ks) {
      short8 pa[4], vb[4];
#pragma unroll
      for (int m = 0; m < 4; ++m) {
        int row = wr * 64 + m * 16 + (lane & 15);
        int p = (ks * 4 + (lane >> 4)) ^ (row & 7);
        pa[m] = *(const short8*)(&Ps[row * 64 + p * 8]);
      }
#pragma unroll
      for (int nn = 0; nn < 4; ++nn) {
        int row = wc * 64 + nn * 16 + (lane & 15);
        int p = (ks * 4 + (lane >> 4)) ^ (row & 7);
        vb[nn] = *(const short8*)(&Vs[row * 64 + p * 8]);
      }
#pragma unroll
      for (int m = 0; m < 4; ++m)
#pragma unroll
        for (int nn = 0; nn < 4; ++nn)
          acco[m][nn] = __builtin_amdgcn_mfma_f32_16x16x32_bf16(pa[m], vb[nn], acco[m][nn], 0, 0, 0);
    }
  }

#pragma unroll
  for (int m = 0; m < 4; ++m) {
#pragma unroll
    for (int nn = 0; nn < 4; ++nn) {
#pragma unroll
      for (int j = 0; j < 4; ++j) {
        int row = wr * 64 + m * 16 + ((lane >> 4) * 4) + j;
        int col = wc * 64 + nn * 16 + (lane & 15);
        Cb[((long)(n >> 4) * Sc + m0 + row) * (long)Dc + (long)(n & 15) * DKc + col] =
            (ushort_t)f2bf(acco[m][nn][j]);
      }
    }
  }
}

// ---------------------------------------------------------------------------
__global__ __launch_bounds__(256)
void cast3_bf16(const float* __restrict__ a, const float* __restrict__ b,
                const float* __restrict__ c, ushort_t* __restrict__ oa,
                ushort_t* __restrict__ ob, ushort_t* __restrict__ oc) {
  const float* in = (blockIdx.y == 0) ? a : (blockIdx.y == 1) ? b : c;
  ushort_t* out = (blockIdx.y == 0) ? oa : (blockIdx.y == 1) ? ob : oc;
  long i = ((long)blockIdx.x * 256 + threadIdx.x) * 8;
  f32x4 x = *(const f32x4*)(in + i);
  f32x4 y = *(const f32x4*)(in + i + 4);
  *(short8*)(out + i) = pack8(x, y);
}

__global__ __launch_bounds__(256)
void castW_bf16(const float* __restrict__ w0, const float* __restrict__ w1,
                const float* __restrict__ w2, const float* __restrict__ w3,
                ushort_t* __restrict__ o0, ushort_t* __restrict__ o1,
                ushort_t* __restrict__ o2, ushort_t* __restrict__ o3) {
  const float* in; ushort_t* out;
  switch (blockIdx.y) {
    case 0: in = w0; out = o0; break;
    case 1: in = w1; out = o1; break;
    case 2: in = w2; out = o2; break;
    default: in = w3; out = o3; break;
  }
  long i = ((long)blockIdx.x * 256 + threadIdx.x) * 8;
  f32x4 x = *(const f32x4*)(in + i);
  f32x4 y = *(const f32x4*)(in + i + 4);
  *(short8*)(out + i) = pack8(x, y);
}

// in-place row layernorm on (8192, 2048) fp32
__global__ __launch_bounds__(256)
void layernorm_rows(float* __restrict__ out, const float* __restrict__ gamma,
                    const float* __restrict__ beta) {
  const long row = blockIdx.x;
  float* p = out + row * (long)Dc;
  const int tid = threadIdx.x;
  const int lane = tid & 63, wave = tid >> 6;
  f32x4 v0 = *(const f32x4*)(p + tid * 8);
  f32x4 v1 = *(const f32x4*)(p + tid * 8 + 4);
  float s = 0.f, ss = 0.f;
#pragma unroll
  for (int e = 0; e < 4; ++e) { s += v0[e]; ss += v0[e] * v0[e]; }
#pragma unroll
  for (int e = 0; e < 4; ++e) { s += v1[e]; ss += v1[e] * v1[e]; }
  for (int off = 32; off > 0; off >>= 1) { s += __shfl_xor(s, off); ss += __shfl_xor(ss, off); }
  __shared__ float rs_[4], rss_[4];
  if (lane == 0) { rs_[wave] = s; rss_[wave] = ss; }
  __syncthreads();
  s  = rs_[0] + rs_[1] + rs_[2] + rs_[3];
  ss = rss_[0] + rss_[1] + rss_[2] + rss_[3];
  const float mean = s * (1.f / Dc);
  const float var  = ss * (1.f / Dc) - mean * mean;
  const float rstd = rsqrtf(var + 1e-6f);
  f32x4 g0 = *(const f32x4*)(gamma + tid * 8);
  f32x4 g1 = *(const f32x4*)(gamma + tid * 8 + 4);
  f32x4 b0 = *(const f32x4*)(beta + tid * 8);
  f32x4 b1 = *(const f32x4*)(beta + tid * 8 + 4);
#pragma unroll
  for (int e = 0; e < 4; ++e) v0[e] = (v0[e] - mean) * rstd * g0[e] + b0[e];
#pragma unroll
  for (int e = 0; e < 4; ++e) v1[e] = (v1[e] - mean) * rstd * g1[e] + b1[e];
  *(f32x4*)(p + tid * 8) = v0;
  *(f32x4*)(p + tid * 8 + 4) = v1;
}

// ---------------------------------------------------------------------------
extern "C" void kernel_launch(void* const* d_in, const int* in_sizes, int n_in,
                              void* d_out, int out_size, void* d_ws, size_t ws_size,
                              hipStream_t stream) {
  (void)in_sizes; (void)n_in; (void)out_size; (void)ws_size;
  const float* q  = (const float*)d_in[0];
  const float* k  = (const float*)d_in[1];
  const float* v  = (const float*)d_in[2];
  const float* Wq = (const float*)d_in[3];
  const float* Wk = (const float*)d_in[4];
  const float* Wv = (const float*)d_in[5];
  const float* Wo = (const float*)d_in[6];
  const float* gamma = (const float*)d_in[7];
  const float* beta  = (const float*)d_in[8];

  float* out  = (float*)d_out;
  float* attn = out + OUT_ELEMS;                // 4.3 GB region (output 1)

  // workspace layout (~168 MB)
  ushort_t* Wqb = (ushort_t*)d_ws;
  ushort_t* Wkb = Wqb + (long)Dc * Dc;
  ushort_t* Wvb = Wkb + (long)Dc * Dc;
  ushort_t* Wob = Wvb + (long)Dc * Dc;
  ushort_t* Qb  = Wob + (long)Dc * Dc;
  ushort_t* Kb  = Qb + OUT_ELEMS;
  ushort_t* VT  = Kb + OUT_ELEMS;
  ushort_t* Cb  = VT + OUT_ELEMS;

  // bf16 copies of q,k,v parked in the attn region (dead before flash writes it)
  ushort_t* qb = (ushort_t*)attn;
  ushort_t* kb = qb + OUT_ELEMS;
  ushort_t* vb = kb + OUT_ELEMS;

  dim3 blk(256);
  cast3_bf16<<<dim3(OUT_ELEMS / 2048, 3), blk, 0, stream>>>(q, k, v, qb, kb, vb);
  castW_bf16<<<dim3((long)Dc * Dc / 2048, 4), blk, 0, stream>>>(
      Wq, Wk, Wv, Wo, Wqb, Wkb, Wvb, Wob);

  // projections (256x256 tiles, grid 8x32)
  gemm256<0><<<dim3(8, 32), dim3(512), 0, stream>>>(qb, Wqb, Qb, nullptr);
  gemm256<0><<<dim3(8, 32), dim3(512), 0, stream>>>(kb, Wkb, Kb, nullptr);
  gemm256<1><<<dim3(8, 32), dim3(512), 0, stream>>>(vb, Wvb, VT, nullptr);

  // flash attention: writes normalized fp32 attn + bf16 context
  flash_attn<<<dim3(1024), blk, 0, stream>>>(Qb, Kb, VT, attn, Cb);

  // output projection + residual
  gemm256<3><<<dim3(8, 32), dim3(512), 0, stream>>>(Cb, Wob, out, q);

  // layernorm in place
  layernorm_rows<<<NTOK, blk, 0, stream>>>(out, gamma, beta);
}

// Round 6
// 718.604 us; speedup vs baseline: 2.1250x; 1.0650x over previous
//
#include <hip/hip_runtime.h>
#include <cstdint>

typedef __attribute__((ext_vector_type(8))) short short8;
typedef __attribute__((ext_vector_type(4))) float f32x4;
typedef __attribute__((ext_vector_type(2))) unsigned u32x2;
typedef unsigned short ushort_t;

constexpr int Bc = 4, Sc = 2048, Dc = 2048, Hc = 16, DKc = 128;
constexpr long NTOK = (long)Bc * Sc;          // 8192 rows
constexpr long OUT_ELEMS = NTOK * (long)Dc;   // 16777216
constexpr float SCALE = 0.08838834764831843f; // 1/sqrt(128)

__device__ __forceinline__ ushort_t f2bf(float f) {
  unsigned u = __builtin_bit_cast(unsigned, f);
  u = (u + 0x7FFFu + ((u >> 16) & 1u)) >> 16;
  return (ushort_t)u;
}

__device__ __forceinline__ short8 pack8(const f32x4& a, const f32x4& b) {
  short8 h;
  h[0] = (short)f2bf(a[0]); h[1] = (short)f2bf(a[1]);
  h[2] = (short)f2bf(a[2]); h[3] = (short)f2bf(a[3]);
  h[4] = (short)f2bf(b[0]); h[5] = (short)f2bf(b[1]);
  h[6] = (short)f2bf(b[2]); h[7] = (short)f2bf(b[3]);
  return h;
}

// async global->LDS, 16B per lane; lds dest is wave-uniform base + lane*16
__device__ __forceinline__ void gl2lds16(const ushort_t* g, ushort_t* l) {
  __builtin_amdgcn_global_load_lds(
      (__attribute__((address_space(1))) unsigned int*)(g),
      (__attribute__((address_space(3))) unsigned int*)(l), 16, 0, 0);
}

__device__ __forceinline__ void bar() {
  asm volatile("" ::: "memory");
  __builtin_amdgcn_s_barrier();
  asm volatile("" ::: "memory");
}

// ---------------------------------------------------------------------------
// Fused 3-projection GEMM, fp32 A source. C = A(8192x2048 fp32)*W(2048x2048)^T.
// 256x256 tile, BK=64, 512 thr (8 waves 2Mx4N), dbuf 128KB LDS.
// A: reg-staged (8x dwordx4 fp32 at P1 -> pack -> 4x ds_write_b128 at P3).
// B: global_load_lds, counted vmcnt(2) at P3.
// z=0: Q proj (bf16 row-major), z=1: K proj, z=2: V proj -> VT transposed.
// ---------------------------------------------------------------------------
__global__ __launch_bounds__(512, 2)
void proj_gemm(const float* __restrict__ qf, const float* __restrict__ kf,
               const float* __restrict__ vf,
               const ushort_t* __restrict__ Wqb, const ushort_t* __restrict__ Wkb,
               const ushort_t* __restrict__ Wvb,
               ushort_t* __restrict__ Qb, ushort_t* __restrict__ Kb,
               ushort_t* __restrict__ VTo)
{
  __shared__ __align__(16) ushort_t SM[2][2][2][128 * 64]; // [A/B][buf][half]

  const int z = blockIdx.z;
  const float* Afull = (z == 0) ? qf : (z == 1) ? kf : vf;
  const ushort_t* Bp = (z == 0) ? Wqb : (z == 1) ? Wkb : Wvb;
  ushort_t* Cp = (z == 0) ? Qb : (z == 1) ? Kb : VTo;

  const int tid = threadIdx.x, lane = tid & 63, wave = tid >> 6;
  const int wm = wave >> 2, wn = wave & 3;

  // bijective XCD swizzle over 256 blocks, grid (8, 32)
  const int lin = blockIdx.y * 8 + blockIdx.x;
  const int swz = (lin & 7) * 32 + (lin >> 3);
  const long n0 = (long)(swz & 7) * 256;
  const long m0 = (long)(swz >> 3) * 256;

  constexpr int NT = 32; // K=2048 / 64

  const float*    Ag = Afull + m0 * (long)Dc;
  const ushort_t* Bg = Bp + n0 * (long)Dc;

  // B half-tile stage: 2 gl2lds per thread
  auto stageB = [&](ushort_t* dst, int kt, int ht) {
#pragma unroll
    for (int c = 0; c < 2; ++c) {
      int U = (c * 8 + wave) * 64 + lane;
      int row = U >> 3, p = U & 7, u = p ^ (row & 7);
      gl2lds16(Bg + (long)(ht * 128 + row) * Dc + kt * 64 + u * 8,
               dst + (c * 8 + wave) * 512);
    }
  };
  // A full-tile fp32 load (8 dwordx4 -> alo/ahi)
  auto loadA = [&](int kt, f32x4 alo[2][2], f32x4 ahi[2][2]) {
#pragma unroll
    for (int ht = 0; ht < 2; ++ht)
#pragma unroll
      for (int c = 0; c < 2; ++c) {
        int U = (c * 8 + wave) * 64 + lane;
        int row = U >> 3, p = U & 7, u = p ^ (row & 7);
        const float* g = Ag + (long)(ht * 128 + row) * Dc + kt * 64 + u * 8;
        alo[ht][c] = *(const f32x4*)g;
        ahi[ht][c] = *(const f32x4*)(g + 4);
      }
  };
  auto writeA = [&](int buf, const f32x4 alo[2][2], const f32x4 ahi[2][2]) {
#pragma unroll
    for (int ht = 0; ht < 2; ++ht)
#pragma unroll
      for (int c = 0; c < 2; ++c) {
        int chunk = c * 8 + wave;
        *(short8*)(&SM[0][buf][ht][chunk * 512 + lane * 8]) =
            pack8(alo[ht][c], ahi[ht][c]);
      }
  };

  // ---- prologue ----
  stageB(&SM[1][0][0][0], 0, 0);
  stageB(&SM[1][0][1][0], 0, 1);
  stageB(&SM[1][1][0][0], 1, 0);
  {
    f32x4 alo[2][2], ahi[2][2];
    loadA(0, alo, ahi);
    asm volatile("s_waitcnt vmcnt(0)" ::: "memory");
    writeA(0, alo, ahi);
    asm volatile("s_waitcnt lgkmcnt(0)" ::: "memory");
  }
  __builtin_amdgcn_s_barrier();
  asm volatile("" ::: "memory");

  f32x4 acc[8][4] = {};

  for (int kt = 0; kt < NT; ++kt) {
    const int cur = kt & 1;
    const ushort_t* Acur = &SM[0][cur][0][0];
    const ushort_t* Bcur = &SM[1][cur][0][0];
    const int k1 = (kt + 1) & (NT - 1);
    const int k2 = (kt + 2) & (NT - 1);
    short8 af[4][2], bq0[2][2], bq1[2][2];
    f32x4 alo[2][2], ahi[2][2];

    // ======== P0: ds af(h0)+bq0; stageB h1(k1) -> buf nxt; MFMA q00 ========
#pragma unroll
    for (int mf = 0; mf < 4; ++mf)
#pragma unroll
      for (int ks = 0; ks < 2; ++ks) {
        int r = mf * 16 + (lane & 15);
        int u = ks * 4 + (lane >> 4), p = u ^ (r & 7);
        af[mf][ks] = *(const short8*)(Acur + wm * (128 * 64) + r * 64 + p * 8);
      }
#pragma unroll
    for (int nf = 0; nf < 2; ++nf)
#pragma unroll
      for (int ks = 0; ks < 2; ++ks) {
        int r = (wn & 1) * 64 + nf * 16 + (lane & 15);
        int u = ks * 4 + (lane >> 4), p = u ^ (r & 7);
        bq0[nf][ks] = *(const short8*)(Bcur + (wn >> 1) * (128 * 64) + r * 64 + p * 8);
      }
    stageB(&SM[1][cur ^ 1][1][0], k1, 1);
    bar();
    __builtin_amdgcn_s_setprio(1);
#pragma unroll
    for (int mf = 0; mf < 4; ++mf)
#pragma unroll
      for (int nf = 0; nf < 2; ++nf)
#pragma unroll
        for (int ks = 0; ks < 2; ++ks)
          acc[mf][nf] = __builtin_amdgcn_mfma_f32_16x16x32_bf16(af[mf][ks], bq0[nf][ks], acc[mf][nf], 0, 0, 0);
    __builtin_amdgcn_s_setprio(0);
    bar();

    // ======== P1: ds bq1; issue A(k1) fp32 loads; MFMA q01 ========
#pragma unroll
    for (int nf = 0; nf < 2; ++nf)
#pragma unroll
      for (int ks = 0; ks < 2; ++ks) {
        int r = (wn & 1) * 64 + 32 + nf * 16 + (lane & 15);
        int u = ks * 4 + (lane >> 4), p = u ^ (r & 7);
        bq1[nf][ks] = *(const short8*)(Bcur + (wn >> 1) * (128 * 64) + r * 64 + p * 8);
      }
    loadA(k1, alo, ahi);
    bar();
    __builtin_amdgcn_s_setprio(1);
#pragma unroll
    for (int mf = 0; mf < 4; ++mf)
#pragma unroll
      for (int nf = 0; nf < 2; ++nf)
#pragma unroll
        for (int ks = 0; ks < 2; ++ks)
          acc[mf][2 + nf] = __builtin_amdgcn_mfma_f32_16x16x32_bf16(af[mf][ks], bq1[nf][ks], acc[mf][2 + nf], 0, 0, 0);
    __builtin_amdgcn_s_setprio(0);
    bar();

    // ======== P2: ds af(h1); stageB h0(k2) -> buf cur; MFMA q10 ========
#pragma unroll
    for (int mf = 0; mf < 4; ++mf)
#pragma unroll
      for (int ks = 0; ks < 2; ++ks) {
        int r = 64 + mf * 16 + (lane & 15);
        int u = ks * 4 + (lane >> 4), p = u ^ (r & 7);
        af[mf][ks] = *(const short8*)(Acur + wm * (128 * 64) + r * 64 + p * 8);
      }
    stageB(&SM[1][cur][0][0], k2, 0);
    bar();
    __builtin_amdgcn_s_setprio(1);
#pragma unroll
    for (int mf = 0; mf < 4; ++mf)
#pragma unroll
      for (int nf = 0; nf < 2; ++nf)
#pragma unroll
        for (int ks = 0; ks < 2; ++ks)
          acc[4 + mf][nf] = __builtin_amdgcn_mfma_f32_16x16x32_bf16(af[mf][ks], bq0[nf][ks], acc[4 + mf][nf], 0, 0, 0);
    __builtin_amdgcn_s_setprio(0);
    bar();

    // ======== P3: vmcnt(2) [A(k1)+B(k1) done]; ds_write A(k1); MFMA q11 ====
    asm volatile("s_waitcnt vmcnt(2)" ::: "memory");
    writeA(cur ^ 1, alo, ahi);
    asm volatile("s_waitcnt lgkmcnt(0)" ::: "memory");
    bar();
    __builtin_amdgcn_s_setprio(1);
#pragma unroll
    for (int mf = 0; mf < 4; ++mf)
#pragma unroll
      for (int nf = 0; nf < 2; ++nf)
#pragma unroll
        for (int ks = 0; ks < 2; ++ks)
          acc[4 + mf][2 + nf] = __builtin_amdgcn_mfma_f32_16x16x32_bf16(af[mf][ks], bq1[nf][ks], acc[4 + mf][2 + nf], 0, 0, 0);
    __builtin_amdgcn_s_setprio(0);
    bar();
  }

  asm volatile("s_waitcnt vmcnt(0)" ::: "memory");

  if (z == 2) {
    // ---- LDS-transpose epilogue: coalesced VT stores ----
    bar();  // all wrapped prefetch gl2lds landed; SM reusable
    char* Tb = (char*)&SM[0][0][0][0];    // 256 rows(cg) x 512B(rg), XOR-swz
#pragma unroll
    for (int mq = 0; mq < 8; ++mq) {
#pragma unroll
      for (int nq = 0; nq < 4; ++nq) {
        int rg = wm * 128 + (mq >> 2) * 64 + (mq & 3) * 16 + ((lane >> 4) * 4);
        int cg = wn * 64 + (nq >> 1) * 32 + (nq & 1) * 16 + (lane & 15);
        u32x2 t;
        t[0] = (unsigned)f2bf(acc[mq][nq][0]) | ((unsigned)f2bf(acc[mq][nq][1]) << 16);
        t[1] = (unsigned)f2bf(acc[mq][nq][2]) | ((unsigned)f2bf(acc[mq][nq][3]) << 16);
        int off = cg * 512 + (((rg >> 3) ^ (cg & 31)) * 16) + (rg & 7) * 2;
        *(u32x2*)(Tb + off) = t;
      }
    }
    bar();
    const long bq = m0 >> 11;
    const long s0 = m0 & 2047;
#pragma unroll
    for (int i = 0; i < 16; ++i) {
      int row = i * 16 + (tid >> 5);     // cg local 0..255
      int un  = tid & 31;                // 16B unit along rg
      int p = un ^ (row & 31);
      short8 val = *(const short8*)(Tb + row * 512 + p * 16);
      long cgg = n0 + row;
      long vtrow = ((cgg >> 7) * 4 + bq) * 128 + (cgg & 127);
      *(short8*)(&Cp[vtrow * (long)Sc + s0 + un * 8]) = val;
    }
  } else {
#pragma unroll
    for (int mq = 0; mq < 8; ++mq) {
#pragma unroll
      for (int nq = 0; nq < 4; ++nq) {
#pragma unroll
        for (int j = 0; j < 4; ++j) {
          long rg = m0 + wm * 128 + (mq >> 2) * 64 + (mq & 3) * 16 + ((lane >> 4) * 4) + j;
          long cg = n0 + wn * 64 + (nq >> 1) * 32 + (nq & 1) * 16 + (lane & 15);
          Cp[rg * (long)Dc + cg] = f2bf(acc[mq][nq][j]);
        }
      }
    }
  }
}

// ---------------------------------------------------------------------------
// Output-projection GEMM (bf16 A=Cb via gl2lds), 256x256 8-phase, fp32 C +
// residual. Same schedule as R5's gemm256<3>.
// ---------------------------------------------------------------------------
__global__ __launch_bounds__(512, 2)
void out_gemm(const ushort_t* __restrict__ Ap, const ushort_t* __restrict__ Bp,
              float* __restrict__ Cp, const float* __restrict__ residual)
{
  __shared__ __align__(16) ushort_t SM[2][2][2][128 * 64];

  const int tid = threadIdx.x, lane = tid & 63, wave = tid >> 6;
  const int wm = wave >> 2, wn = wave & 3;
  const int lin = blockIdx.y * 8 + blockIdx.x;
  const int swz = (lin & 7) * 32 + (lin >> 3);
  const long n0 = (long)(swz & 7) * 256;
  const long m0 = (long)(swz >> 3) * 256;
  constexpr int NT = 32;

  const ushort_t* Ag = Ap + m0 * (long)Dc;
  const ushort_t* Bg = Bp + n0 * (long)Dc;

  auto stage = [&](const ushort_t* gb, ushort_t* dst, int kt, int ht) {
#pragma unroll
    for (int c = 0; c < 2; ++c) {
      int U = (c * 8 + wave) * 64 + lane;
      int row = U >> 3, p = U & 7, u = p ^ (row & 7);
      gl2lds16(gb + (long)(ht * 128 + row) * Dc + kt * 64 + u * 8,
               dst + (c * 8 + wave) * 512);
    }
  };

  stage(Bg, &SM[1][0][0][0], 0, 0);
  stage(Ag, &SM[0][0][0][0], 0, 0);
  stage(Bg, &SM[1][0][1][0], 0, 1);
  stage(Ag, &SM[0][0][1][0], 0, 1);
  stage(Bg, &SM[1][1][0][0], 1, 0);
  stage(Ag, &SM[0][1][0][0], 1, 0);
  asm volatile("s_waitcnt vmcnt(4)" ::: "memory");
  __builtin_amdgcn_s_barrier();
  asm volatile("" ::: "memory");

  f32x4 acc[8][4] = {};

  for (int kt = 0; kt < NT; ++kt) {
    const int cur = kt & 1;
    const ushort_t* Acur = &SM[0][cur][0][0];
    const ushort_t* Bcur = &SM[1][cur][0][0];
    const int k1 = (kt + 1) & (NT - 1);
    const int k2 = (kt + 2) & (NT - 1);
    short8 af[4][2], bq0[2][2], bq1[2][2];

#pragma unroll
    for (int mf = 0; mf < 4; ++mf)
#pragma unroll
      for (int ks = 0; ks < 2; ++ks) {
        int r = mf * 16 + (lane & 15);
        int u = ks * 4 + (lane >> 4), p = u ^ (r & 7);
        af[mf][ks] = *(const short8*)(Acur + wm * (128 * 64) + r * 64 + p * 8);
      }
#pragma unroll
    for (int nf = 0; nf < 2; ++nf)
#pragma unroll
      for (int ks = 0; ks < 2; ++ks) {
        int r = (wn & 1) * 64 + nf * 16 + (lane & 15);
        int u = ks * 4 + (lane >> 4), p = u ^ (r & 7);
        bq0[nf][ks] = *(const short8*)(Bcur + (wn >> 1) * (128 * 64) + r * 64 + p * 8);
      }
    stage(Bg, &SM[1][cur ^ 1][1][0], k1, 1);
    bar();
    __builtin_amdgcn_s_setprio(1);
#pragma unroll
    for (int mf = 0; mf < 4; ++mf)
#pragma unroll
      for (int nf = 0; nf < 2; ++nf)
#pragma unroll
        for (int ks = 0; ks < 2; ++ks)
          acc[mf][nf] = __builtin_amdgcn_mfma_f32_16x16x32_bf16(af[mf][ks], bq0[nf][ks], acc[mf][nf], 0, 0, 0);
    __builtin_amdgcn_s_setprio(0);
    bar();

#pragma unroll
    for (int nf = 0; nf < 2; ++nf)
#pragma unroll
      for (int ks = 0; ks < 2; ++ks) {
        int r = (wn & 1) * 64 + 32 + nf * 16 + (lane & 15);
        int u = ks * 4 + (lane >> 4), p = u ^ (r & 7);
        bq1[nf][ks] = *(const short8*)(Bcur + (wn >> 1) * (128 * 64) + r * 64 + p * 8);
      }
    stage(Ag, &SM[0][cur ^ 1][1][0], k1, 1);
    bar();
    __builtin_amdgcn_s_setprio(1);
#pragma unroll
    for (int mf = 0; mf < 4; ++mf)
#pragma unroll
      for (int nf = 0; nf < 2; ++nf)
#pragma unroll
        for (int ks = 0; ks < 2; ++ks)
          acc[mf][2 + nf] = __builtin_amdgcn_mfma_f32_16x16x32_bf16(af[mf][ks], bq1[nf][ks], acc[mf][2 + nf], 0, 0, 0);
    __builtin_amdgcn_s_setprio(0);
    bar();

#pragma unroll
    for (int mf = 0; mf < 4; ++mf)
#pragma unroll
      for (int ks = 0; ks < 2; ++ks) {
        int r = 64 + mf * 16 + (lane & 15);
        int u = ks * 4 + (lane >> 4), p = u ^ (r & 7);
        af[mf][ks] = *(const short8*)(Acur + wm * (128 * 64) + r * 64 + p * 8);
      }
    stage(Bg, &SM[1][cur][0][0], k2, 0);
    bar();
    __builtin_amdgcn_s_setprio(1);
#pragma unroll
    for (int mf = 0; mf < 4; ++mf)
#pragma unroll
      for (int nf = 0; nf < 2; ++nf)
#pragma unroll
        for (int ks = 0; ks < 2; ++ks)
          acc[4 + mf][nf] = __builtin_amdgcn_mfma_f32_16x16x32_bf16(af[mf][ks], bq0[nf][ks], acc[4 + mf][nf], 0, 0, 0);
    __builtin_amdgcn_s_setprio(0);
    bar();

    stage(Ag, &SM[0][cur][0][0], k2, 0);
    asm volatile("s_waitcnt vmcnt(4)" ::: "memory");
    bar();
    __builtin_amdgcn_s_setprio(1);
#pragma unroll
    for (int mf = 0; mf < 4; ++mf)
#pragma unroll
      for (int nf = 0; nf < 2; ++nf)
#pragma unroll
        for (int ks = 0; ks < 2; ++ks)
          acc[4 + mf][2 + nf] = __builtin_amdgcn_mfma_f32_16x16x32_bf16(af[mf][ks], bq1[nf][ks], acc[4 + mf][2 + nf], 0, 0, 0);
    __builtin_amdgcn_s_setprio(0);
    bar();
  }

  asm volatile("s_waitcnt vmcnt(0)" ::: "memory");

#pragma unroll
  for (int mq = 0; mq < 8; ++mq) {
#pragma unroll
    for (int nq = 0; nq < 4; ++nq) {
#pragma unroll
      for (int j = 0; j < 4; ++j) {
        long rg = m0 + wm * 128 + (mq >> 2) * 64 + (mq & 3) * 16 + ((lane >> 4) * 4) + j;
        long cg = n0 + wn * 64 + (nq >> 1) * 32 + (nq & 1) * 16 + (lane & 15);
        Cp[rg * (long)Dc + cg] = acc[mq][nq][j] + residual[rg * (long)Dc + cg];
      }
    }
  }
}

// ---------------------------------------------------------------------------
// Flash attention, T14 reg-staged pipeline; nontemporal P stores.
// ---------------------------------------------------------------------------
__global__ __launch_bounds__(256, 2)
void flash_attn(const ushort_t* __restrict__ Qb, const ushort_t* __restrict__ Kb,
                const ushort_t* __restrict__ VT, float* __restrict__ attn,
                ushort_t* __restrict__ Cb)
{
  __shared__ __align__(16) ushort_t Qs[128 * 128]; // swz u^(row&15)
  __shared__ __align__(16) ushort_t Ks[64 * 128];  // swz u^(row&15)
  __shared__ __align__(16) ushort_t Vs[128 * 64];  // swz u^(row&7)
  __shared__ __align__(16) ushort_t Ps[128 * 64];  // swz u^(row&7)

  const int tid = threadIdx.x, lane = tid & 63, wave = tid >> 6;
  const int wr = wave >> 1, wc = wave & 1;

  const int bid = blockIdx.x;
  const int xcd = bid & 7, slot = bid >> 3;
  const int n = xcd * 8 + (slot >> 4);
  const long m0 = (long)(slot & 15) * 128;
  const int b = n & 3, h = n >> 2;

  const ushort_t* Qg = Qb + ((long)b * Sc) * Dc + (long)h * DKc;
  const ushort_t* Kg = Kb + ((long)b * Sc) * Dc + (long)h * DKc;
  const ushort_t* Vg = VT + (long)n * DKc * (long)Sc;
  float* Pg = attn + (long)n * Sc * (long)Sc;

#pragma unroll
  for (int c8 = 0; c8 < 8; ++c8) {
    int chunk = c8 * 4 + wave;
    int U = chunk * 64 + lane;
    int row = U >> 4, p = U & 15, u = p ^ (row & 15);
    gl2lds16(Qg + (m0 + row) * (long)Dc + u * 8, &Qs[chunk * 512]);
  }

  auto kaddr = [&](int t, int c4) -> const short8* {
    int chunk = c4 * 4 + wave;
    int U = chunk * 64 + lane;
    int row = U >> 4, p = U & 15, u = p ^ (row & 15);
    return (const short8*)(Kg + ((long)t * 64 + row) * (long)Dc + u * 8);
  };
  auto vaddr = [&](int t, int c4) -> const short8* {
    int chunk = c4 * 4 + wave;
    int U = chunk * 64 + lane;
    int row = U >> 3, p = U & 7, u = p ^ (row & 7);
    return (const short8*)(Vg + (long)row * Sc + (long)t * 64 + u * 8);
  };

  float rs[4][4] = {};

  // ---- Loop A ----
  short8 kr0 = *kaddr(0, 0), kr1 = *kaddr(0, 1), kr2_ = *kaddr(0, 2), kr3 = *kaddr(0, 3);
  for (int t = 0; t < 32; ++t) {
    __syncthreads();
    *(short8*)(&Ks[(0 * 4 + wave) * 512 + lane * 8]) = kr0;
    *(short8*)(&Ks[(1 * 4 + wave) * 512 + lane * 8]) = kr1;
    *(short8*)(&Ks[(2 * 4 + wave) * 512 + lane * 8]) = kr2_;
    *(short8*)(&Ks[(3 * 4 + wave) * 512 + lane * 8]) = kr3;
    {
      int tn = (t + 1) & 31;
      kr0 = *kaddr(tn, 0); kr1 = *kaddr(tn, 1);
      kr2_ = *kaddr(tn, 2); kr3 = *kaddr(tn, 3);
    }
    __syncthreads();
    f32x4 acc[4][2] = {};
#pragma unroll
    for (int kk = 0; kk < 4; ++kk) {
      short8 af[4], bfr[2];
#pragma unroll
      for (int m = 0; m < 4; ++m) {
        int row = wr * 64 + m * 16 + (lane & 15);
        int p = (kk * 4 + (lane >> 4)) ^ (row & 15);
        af[m] = *(const short8*)(&Qs[row * 128 + p * 8]);
      }
#pragma unroll
      for (int nn = 0; nn < 2; ++nn) {
        int row = wc * 32 + nn * 16 + (lane & 15);
        int p = (kk * 4 + (lane >> 4)) ^ (row & 15);
        bfr[nn] = *(const short8*)(&Ks[row * 128 + p * 8]);
      }
#pragma unroll
      for (int m = 0; m < 4; ++m)
#pragma unroll
        for (int nn = 0; nn < 2; ++nn)
          acc[m][nn] = __builtin_amdgcn_mfma_f32_16x16x32_bf16(af[m], bfr[nn], acc[m][nn], 0, 0, 0);
    }
#pragma unroll
    for (int m = 0; m < 4; ++m)
#pragma unroll
      for (int nn = 0; nn < 2; ++nn)
#pragma unroll
        for (int j = 0; j < 4; ++j)
          rs[m][j] += __expf(acc[m][nn][j] * SCALE);
  }

  short8 k0 = *kaddr(0, 0), k1_ = *kaddr(0, 1), k2_ = *kaddr(0, 2), k3 = *kaddr(0, 3);
  short8 v0 = *vaddr(0, 0), v1 = *vaddr(0, 1), v2 = *vaddr(0, 2), v3 = *vaddr(0, 3);

  float* red = (float*)Ps;
#pragma unroll
  for (int m = 0; m < 4; ++m)
#pragma unroll
    for (int j = 0; j < 4; ++j) {
#pragma unroll
      for (int off = 1; off < 16; off <<= 1)
        rs[m][j] += __shfl_xor(rs[m][j], off);
    }
  __syncthreads();
  if ((lane & 15) == 0) {
#pragma unroll
    for (int m = 0; m < 4; ++m)
#pragma unroll
      for (int j = 0; j < 4; ++j)
        red[wc * 128 + wr * 64 + m * 16 + ((lane >> 4) * 4) + j] = rs[m][j];
  }
  __syncthreads();
  float invl[4][4];
#pragma unroll
  for (int m = 0; m < 4; ++m)
#pragma unroll
    for (int j = 0; j < 4; ++j) {
      int row = wr * 64 + m * 16 + ((lane >> 4) * 4) + j;
      invl[m][j] = 1.f / (red[row] + red[128 + row]);
    }

  // ---- Loop B ----
  f32x4 acco[4][4] = {};
  for (int t = 0; t < 32; ++t) {
    __syncthreads();
    *(short8*)(&Ks[(0 * 4 + wave) * 512 + lane * 8]) = k0;
    *(short8*)(&Ks[(1 * 4 + wave) * 512 + lane * 8]) = k1_;
    *(short8*)(&Ks[(2 * 4 + wave) * 512 + lane * 8]) = k2_;
    *(short8*)(&Ks[(3 * 4 + wave) * 512 + lane * 8]) = k3;
    *(short8*)(&Vs[(0 * 4 + wave) * 512 + lane * 8]) = v0;
    *(short8*)(&Vs[(1 * 4 + wave) * 512 + lane * 8]) = v1;
    *(short8*)(&Vs[(2 * 4 + wave) * 512 + lane * 8]) = v2;
    *(short8*)(&Vs[(3 * 4 + wave) * 512 + lane * 8]) = v3;
    {
      int tn = (t + 1) & 31;
      k0 = *kaddr(tn, 0); k1_ = *kaddr(tn, 1); k2_ = *kaddr(tn, 2); k3 = *kaddr(tn, 3);
      v0 = *vaddr(tn, 0); v1 = *vaddr(tn, 1); v2 = *vaddr(tn, 2); v3 = *vaddr(tn, 3);
    }
    __syncthreads();
    f32x4 acc[4][2] = {};
#pragma unroll
    for (int kk = 0; kk < 4; ++kk) {
      short8 af[4], bfr[2];
#pragma unroll
      for (int m = 0; m < 4; ++m) {
        int row = wr * 64 + m * 16 + (lane & 15);
        int p = (kk * 4 + (lane >> 4)) ^ (row & 15);
        af[m] = *(const short8*)(&Qs[row * 128 + p * 8]);
      }
#pragma unroll
      for (int nn = 0; nn < 2; ++nn) {
        int row = wc * 32 + nn * 16 + (lane & 15);
        int p = (kk * 4 + (lane >> 4)) ^ (row & 15);
        bfr[nn] = *(const short8*)(&Ks[row * 128 + p * 8]);
      }
#pragma unroll
      for (int m = 0; m < 4; ++m)
#pragma unroll
        for (int nn = 0; nn < 2; ++nn)
          acc[m][nn] = __builtin_amdgcn_mfma_f32_16x16x32_bf16(af[m], bfr[nn], acc[m][nn], 0, 0, 0);
    }
#pragma unroll
    for (int m = 0; m < 4; ++m) {
#pragma unroll
      for (int nn = 0; nn < 2; ++nn) {
#pragma unroll
        for (int j = 0; j < 4; ++j) {
          float e = __expf(acc[m][nn][j] * SCALE) * invl[m][j];
          int row = wr * 64 + m * 16 + ((lane >> 4) * 4) + j;
          int col = wc * 32 + nn * 16 + (lane & 15);
          __builtin_nontemporal_store(e, &Pg[(m0 + row) * (long)Sc + (long)t * 64 + col]);
          int pp = (col >> 3) ^ (row & 7);
          Ps[row * 64 + pp * 8 + (col & 7)] = (ushort_t)f2bf(e);
        }
      }
    }
    __syncthreads();
#pragma unroll
    for (int ks = 0; ks < 2; ++ks) {
      short8 pa[4], vb[4];
#pragma unroll
      for (int m = 0; m < 4; ++m) {
        int row = wr * 64 + m * 16 + (lane & 15);
        int p = (ks * 4 + (lane >> 4)) ^ (row & 7);
        pa[m] = *(const short8*)(&Ps[row * 64 + p * 8]);
      }
#pragma unroll
      for (int nn = 0; nn < 4; ++nn) {
        int row = wc * 64 + nn * 16 + (lane & 15);
        int p = (ks * 4 + (lane >> 4)) ^ (row & 7);
        vb[nn] = *(const short8*)(&Vs[row * 64 + p * 8]);
      }
#pragma unroll
      for (int m = 0; m < 4; ++m)
#pragma unroll
        for (int nn = 0; nn < 4; ++nn)
          acco[m][nn] = __builtin_amdgcn_mfma_f32_16x16x32_bf16(pa[m], vb[nn], acco[m][nn], 0, 0, 0);
    }
  }

#pragma unroll
  for (int m = 0; m < 4; ++m) {
#pragma unroll
    for (int nn = 0; nn < 4; ++nn) {
#pragma unroll
      for (int j = 0; j < 4; ++j) {
        int row = wr * 64 + m * 16 + ((lane >> 4) * 4) + j;
        int col = wc * 64 + nn * 16 + (lane & 15);
        Cb[((long)(n >> 4) * Sc + m0 + row) * (long)Dc + (long)(n & 15) * DKc + col] =
            (ushort_t)f2bf(acco[m][nn][j]);
      }
    }
  }
}

// ---------------------------------------------------------------------------
__global__ __launch_bounds__(256)
void castW_bf16(const float* __restrict__ w0, const float* __restrict__ w1,
                const float* __restrict__ w2, const float* __restrict__ w3,
                ushort_t* __restrict__ o0, ushort_t* __restrict__ o1,
                ushort_t* __restrict__ o2, ushort_t* __restrict__ o3) {
  const float* in; ushort_t* out;
  switch (blockIdx.y) {
    case 0: in = w0; out = o0; break;
    case 1: in = w1; out = o1; break;
    case 2: in = w2; out = o2; break;
    default: in = w3; out = o3; break;
  }
  long i = ((long)blockIdx.x * 256 + threadIdx.x) * 8;
  f32x4 x = *(const f32x4*)(in + i);
  f32x4 y = *(const f32x4*)(in + i + 4);
  *(short8*)(out + i) = pack8(x, y);
}

// in-place row layernorm on (8192, 2048) fp32
__global__ __launch_bounds__(256)
void layernorm_rows(float* __restrict__ out, const float* __restrict__ gamma,
                    const float* __restrict__ beta) {
  const long row = blockIdx.x;
  float* p = out + row * (long)Dc;
  const int tid = threadIdx.x;
  const int lane = tid & 63, wave = tid >> 6;
  f32x4 v0 = *(const f32x4*)(p + tid * 8);
  f32x4 v1 = *(const f32x4*)(p + tid * 8 + 4);
  float s = 0.f, ss = 0.f;
#pragma unroll
  for (int e = 0; e < 4; ++e) { s += v0[e]; ss += v0[e] * v0[e]; }
#pragma unroll
  for (int e = 0; e < 4; ++e) { s += v1[e]; ss += v1[e] * v1[e]; }
  for (int off = 32; off > 0; off >>= 1) { s += __shfl_xor(s, off); ss += __shfl_xor(ss, off); }
  __shared__ float rs_[4], rss_[4];
  if (lane == 0) { rs_[wave] = s; rss_[wave] = ss; }
  __syncthreads();
  s  = rs_[0] + rs_[1] + rs_[2] + rs_[3];
  ss = rss_[0] + rss_[1] + rss_[2] + rss_[3];
  const float mean = s * (1.f / Dc);
  const float var  = ss * (1.f / Dc) - mean * mean;
  const float rstd = rsqrtf(var + 1e-6f);
  f32x4 g0 = *(const f32x4*)(gamma + tid * 8);
  f32x4 g1 = *(const f32x4*)(gamma + tid * 8 + 4);
  f32x4 b0 = *(const f32x4*)(beta + tid * 8);
  f32x4 b1 = *(const f32x4*)(beta + tid * 8 + 4);
#pragma unroll
  for (int e = 0; e < 4; ++e) v0[e] = (v0[e] - mean) * rstd * g0[e] + b0[e];
#pragma unroll
  for (int e = 0; e < 4; ++e) v1[e] = (v1[e] - mean) * rstd * g1[e] + b1[e];
  *(f32x4*)(p + tid * 8) = v0;
  *(f32x4*)(p + tid * 8 + 4) = v1;
}

// ---------------------------------------------------------------------------
extern "C" void kernel_launch(void* const* d_in, const int* in_sizes, int n_in,
                              void* d_out, int out_size, void* d_ws, size_t ws_size,
                              hipStream_t stream) {
  (void)in_sizes; (void)n_in; (void)out_size; (void)ws_size;
  const float* q  = (const float*)d_in[0];
  const float* k  = (const float*)d_in[1];
  const float* v  = (const float*)d_in[2];
  const float* Wq = (const float*)d_in[3];
  const float* Wk = (const float*)d_in[4];
  const float* Wv = (const float*)d_in[5];
  const float* Wo = (const float*)d_in[6];
  const float* gamma = (const float*)d_in[7];
  const float* beta  = (const float*)d_in[8];

  float* out  = (float*)d_out;
  float* attn = out + OUT_ELEMS;                // 4.3 GB region (output 1)

  // workspace layout (~168 MB)
  ushort_t* Wqb = (ushort_t*)d_ws;
  ushort_t* Wkb = Wqb + (long)Dc * Dc;
  ushort_t* Wvb = Wkb + (long)Dc * Dc;
  ushort_t* Wob = Wvb + (long)Dc * Dc;
  ushort_t* Qb  = Wob + (long)Dc * Dc;
  ushort_t* Kb  = Qb + OUT_ELEMS;
  ushort_t* VT  = Kb + OUT_ELEMS;
  ushort_t* Cb  = VT + OUT_ELEMS;

  // weight casts (bf16 B operands)
  castW_bf16<<<dim3((long)Dc * Dc / 2048, 4), dim3(256), 0, stream>>>(
      Wq, Wk, Wv, Wo, Wqb, Wkb, Wvb, Wob);

  // fused 3-projection GEMM, fp32 A direct (grid.z = q/k/v)
  proj_gemm<<<dim3(8, 32, 3), dim3(512), 0, stream>>>(
      q, k, v, Wqb, Wkb, Wvb, Qb, Kb, VT);

  // flash attention: writes normalized fp32 attn (nt) + bf16 context
  flash_attn<<<dim3(1024), dim3(256), 0, stream>>>(Qb, Kb, VT, attn, Cb);

  // output projection + residual
  out_gemm<<<dim3(8, 32), dim3(512), 0, stream>>>(Cb, Wob, out, q);

  // layernorm in place
  layernorm_rows<<<NTOK, dim3(256), 0, stream>>>(out, gamma, beta);
}